// Round 9
// baseline (285.494 us; speedup 1.0000x reference)
//
#include <hip/hip_runtime.h>
#include <stdint.h>

#define Bb 4
#define Ss 2048
#define Dd 1024
#define Hh 16
#define DKk 64
#define Mm (Bb * Ss)  // 8192

typedef __attribute__((ext_vector_type(4))) float f32x4;
typedef __attribute__((ext_vector_type(16))) float f32x16;
typedef __attribute__((ext_vector_type(4))) float f4v;
typedef __attribute__((ext_vector_type(8))) unsigned short us8;
typedef __attribute__((ext_vector_type(4))) unsigned short us4;
typedef __attribute__((ext_vector_type(8))) __bf16 bf16x8;

__device__ __forceinline__ unsigned short bfbits(__bf16 x) {
  union { __bf16 b; unsigned short u; } v; v.b = x; return v.u;
}
__device__ __forceinline__ uint32_t packbf(float lo, float hi) {
  union { __bf16 b[2]; uint32_t u; } v;
  v.b[0] = (__bf16)lo; v.b[1] = (__bf16)hi;
  return v.u;
}
// v_permlane32_swap_b32: a[32:63] <-> b[0:31]  (in-place, both operands)
__device__ __forceinline__ void plswap(uint32_t& a, uint32_t& b) {
  asm("v_permlane32_swap_b32 %0, %1" : "+v"(a), "+v"(b));
}
// async global->LDS, 16B per lane; LDS dest = wave-uniform base + lane*16
__device__ __forceinline__ void gl16(const unsigned short* g, unsigned short* l) {
  __builtin_amdgcn_global_load_lds(
      (__attribute__((address_space(1))) void*)(g),
      (__attribute__((address_space(3))) void*)(l), 16, 0, 0);
}

// ---------------- fp32 -> bf16 hi/lo split (weights) ----------------
__global__ __launch_bounds__(256)
void split_hilo(const float* __restrict__ x, unsigned short* __restrict__ hi,
                unsigned short* __restrict__ lo, int n4) {
  int i = blockIdx.x * 256 + threadIdx.x;
  if (i >= n4) return;
  f4v v = *(const f4v*)(x + (size_t)i * 4);
  us4 h, l;
#pragma unroll
  for (int j = 0; j < 4; ++j) {
    __bf16 hb = (__bf16)v[j];
    h[j] = bfbits(hb);
    l[j] = bfbits((__bf16)(v[j] - (float)hb));
  }
  *(us4*)(hi + (size_t)i * 4) = h;
  *(us4*)(lo + (size_t)i * 4) = l;
}

// ---------------- fp32 -> bf16 round (activations) ----------------
__global__ __launch_bounds__(256)
void cvt_bf16(const float* __restrict__ x, unsigned short* __restrict__ out, int n4) {
  int i = blockIdx.x * 256 + threadIdx.x;
  if (i >= n4) return;
  f4v v = *(const f4v*)(x + (size_t)i * 4);
  us4 h;
#pragma unroll
  for (int j = 0; j < 4; ++j) h[j] = bfbits((__bf16)v[j]);
  *(us4*)(out + (size_t)i * 4) = h;
}

// ---------------- GEMM v2: out[M,N] = A[M,K] . B[N,K]^T + bias ----------------
// m97 structure: 128x128 tile, BK=64, single-buffered LINEAR LDS staged via
// global_load_lds (pre-swizzled global source), XOR-swizzled ds_read_b128
// fragments, 2 barriers/K-step. A plain bf16; B split hi/lo if BSPLIT.
template <bool BSPLIT, bool OUT_BF16>
__global__ __launch_bounds__(256)
void gemm_bt(const unsigned short* __restrict__ A,
             const unsigned short* __restrict__ Bh, const unsigned short* __restrict__ Bl,
             const float* __restrict__ bias, void* __restrict__ outp,
             int Kdim, int Ndim, float scale) {
  __shared__ unsigned short Ath[128 * 64];
  __shared__ unsigned short Bth[128 * 64];
  __shared__ unsigned short Btl[BSPLIT ? 128 * 64 : 8];

  const int tid = threadIdx.x;
  const int wave = tid >> 6, lane = tid & 63, g = lane >> 4, ln = lane & 15;
  const int wr = wave >> 1, wc = wave & 1;
  int dd = blockIdx.x;
  int orig = (dd & 7) * 64 + (dd >> 3);   // XCD swizzle (512 = 8 * 64)
  const int bm = (orig >> 3) * 128;
  const int bn = (orig & 7) * 128;

  const int srow = lane >> 3;
  const int schunk = (lane & 7) ^ srow;

  f32x4 acc[4][4] = {};

  for (int k0 = 0; k0 < Kdim; k0 += 64) {
    __syncthreads();
#pragma unroll
    for (int ii = 0; ii < 4; ++ii) {
      const int rA = wave * 32 + ii * 8;
      gl16(&A [(size_t)(bm + rA + srow) * Kdim + k0 + schunk * 8], &Ath[rA * 64]);
      gl16(&Bh[(size_t)(bn + rA + srow) * Kdim + k0 + schunk * 8], &Bth[rA * 64]);
      if constexpr (BSPLIT) {
        gl16(&Bl[(size_t)(bn + rA + srow) * Kdim + k0 + schunk * 8], &Btl[rA * 64]);
      }
    }
    __syncthreads();

#pragma unroll
    for (int ko = 0; ko < 2; ++ko) {
      bf16x8 ah[4], bh[4], bl[4];
#pragma unroll
      for (int i = 0; i < 4; ++i) {
        const int ra = wr * 64 + i * 16 + ln;
        const int rb = wc * 64 + i * 16 + ln;
        ah[i] = *(const bf16x8*)&Ath[ra * 64 + ((ko * 4 + g) ^ (ra & 7)) * 8];
        bh[i] = *(const bf16x8*)&Bth[rb * 64 + ((ko * 4 + g) ^ (rb & 7)) * 8];
        if constexpr (BSPLIT) {
          bl[i] = *(const bf16x8*)&Btl[rb * 64 + ((ko * 4 + g) ^ (rb & 7)) * 8];
        }
      }
#pragma unroll
      for (int i = 0; i < 4; ++i)
#pragma unroll
        for (int j = 0; j < 4; ++j) {
          acc[i][j] = __builtin_amdgcn_mfma_f32_16x16x32_bf16(ah[i], bh[j], acc[i][j], 0, 0, 0);
          if constexpr (BSPLIT) {
            acc[i][j] = __builtin_amdgcn_mfma_f32_16x16x32_bf16(ah[i], bl[j], acc[i][j], 0, 0, 0);
          }
        }
    }
  }

  float bvals[4];
#pragma unroll
  for (int j = 0; j < 4; ++j) bvals[j] = bias[bn + wc * 64 + j * 16 + ln];

#pragma unroll
  for (int i = 0; i < 4; ++i) {
    int row0 = bm + wr * 64 + i * 16 + g * 4;
#pragma unroll
    for (int j = 0; j < 4; ++j) {
      int col = bn + wc * 64 + j * 16 + ln;
#pragma unroll
      for (int r = 0; r < 4; ++r) {
        float vv = (acc[i][j][r] + bvals[j]) * scale;
        if constexpr (OUT_BF16) {
          ((unsigned short*)outp)[(size_t)(row0 + r) * Ndim + col] = bfbits((__bf16)vv);
        } else {
          ((float*)outp)[(size_t)(row0 + r) * Ndim + col] = vv;
        }
      }
    }
  }
}

// ---------------- V transpose: [B,S,D] -> [B,D,S] (bf16) ----------------
__global__ __launch_bounds__(256)
void transpose_v(const unsigned short* __restrict__ Vb, unsigned short* __restrict__ VT) {
  __shared__ unsigned short tb[64 * 72];
  int s0 = blockIdx.x * 64, d0 = blockIdx.y * 64, b = blockIdx.z;
  int tid = threadIdx.x;
#pragma unroll
  for (int chi = 0; chi < 2; ++chi) {
    int c = tid + chi * 256;
    int r = c >> 3, cc = (c & 7) * 8;
    *(us8*)&tb[r * 72 + cc] = *(const us8*)&Vb[((size_t)b * Ss + s0 + r) * Dd + d0 + cc];
  }
  __syncthreads();
#pragma unroll
  for (int chi = 0; chi < 2; ++chi) {
    int c = tid + chi * 256;
    int r = c >> 3, cc = (c & 7) * 8;  // r: d row of out tile, cc: s offset
    us8 o;
#pragma unroll
    for (int j = 0; j < 8; ++j) o[j] = tb[(cc + j) * 72 + r];
    *(us8*)&VT[((size_t)b * Dd + d0 + r) * Ss + s0 + cc] = o;
  }
}

// ---------------- fused flash attention v6 (32x32x16, q x kv wave split) ----
// QBLK=128, grid 1024, XCD-swizzled. 4 waves = (wq:2) x (wk:2): wave owns
// 64 q rows (2 q-sets) x its 32-kv half. K frags (4 b128) and V frags
// (4 b128) loaded ONCE per tile, shared across both q-sets -> 8 b128/tile
// /wave (was 16). Partial O over kv-halves pair-summed at epilogue through
// the dead K/V LDS buffers; l merged via small lbuf. Fixed-max softmax,
// native exp2, P in regs via permlane32_swap, l-sums on the MFMA pipe.
__global__ __launch_bounds__(256, 2)
void attn_fused(const unsigned short* __restrict__ Qb, const unsigned short* __restrict__ Kb,
                const unsigned short* __restrict__ VT, unsigned short* __restrict__ xb) {
  __shared__ unsigned short Ks[2][64 * 64];
  __shared__ unsigned short Vs[2][64 * 64];   // V^T tile: [d][kv]
  __shared__ float lbuf[2][64];

  const int tid = threadIdx.x, wave = tid >> 6, lane = tid & 63;
  const int lq = lane & 31, hi = lane >> 5;
  const int wq = wave >> 1, wk = wave & 1;
  const int swzc = (lane & 7) ^ ((lane >> 3) & 7);  // pre-swizzled source chunk

  int dd = blockIdx.x;
  int orig = (dd & 7) * 128 + (dd >> 3);  // XCD swizzle (1024 = 8 * 128)
  const int bh = orig >> 4, qb = orig & 15;
  const int q0 = qb * 128;
  const int b = bh >> 4, h = bh & 15;

  const size_t rowBase = (size_t)b * Ss * Dd + (size_t)h * DKk;
  const size_t vtBase  = ((size_t)b * Dd + h * DKk) * Ss;

  // Q B-operand frags for both q-sets (once)
  bf16x8 qf[2][4];
#pragma unroll
  for (int qs = 0; qs < 2; ++qs) {
    const unsigned short* qrow =
        Qb + rowBase + (size_t)(q0 + wq * 64 + qs * 32 + lq) * Dd + 8 * hi;
#pragma unroll
    for (int c = 0; c < 4; ++c) qf[qs][c] = *(const bf16x8*)(qrow + 16 * c);
  }

  // ones fragment for the l-row-sum MFMA
  bf16x8 ones;
#pragma unroll
  for (int j = 0; j < 8; ++j) ones[j] = (__bf16)1.0f;

  f32x16 accO[2][2] = {};   // [qs][ds], partial over this wave's kv half
  f32x16 acc_l[2] = {};     // partial row sums

  // stage tile t into buffer nb: each wave covers rows [wave*16, wave*16+16)
  const int i0 = wave * 2;
  auto stage = [&](int t, int nb) {
#pragma unroll
    for (int ii = 0; ii < 2; ++ii) {
      const int i = i0 + ii;
      const int rr = i * 8 + (lane >> 3);
      gl16(&Kb[rowBase + (size_t)(t * 64 + rr) * Dd + swzc * 8], &Ks[nb][i * 512]);
      gl16(&VT[vtBase + (size_t)rr * Ss + t * 64 + swzc * 8], &Vs[nb][i * 512]);
    }
  };

  stage(0, 0);

  for (int t = 0; t < 32; ++t) {
    const int cur = t & 1;
    __syncthreads();   // vmcnt(0) drain -> buf[cur] ready; done reading buf[1-cur]
    if (t + 1 < 32) stage(t + 1, 1 - cur);

    // K frags for this wave's kv-half (shared across q-sets)
    bf16x8 kf[4];
#pragma unroll
    for (int c = 0; c < 4; ++c)
      kf[c] = *(const bf16x8*)
          &Ks[cur][(wk * 32 + lq) * 64 + ((2 * c + hi) ^ (lq & 7)) * 8];
    // V frags for this wave's kv-half (shared across q-sets)
    bf16x8 vf[2][2];
#pragma unroll
    for (int ds = 0; ds < 2; ++ds)
#pragma unroll
      for (int m = 0; m < 2; ++m)
        vf[ds][m] = *(const bf16x8*)
            &Vs[cur][(ds * 32 + lq) * 64 + ((2 * (2 * wk + m) + hi) ^ (lq & 7)) * 8];

#pragma unroll
    for (int qs = 0; qs < 2; ++qs) {
      f32x16 z = {};
#pragma unroll
      for (int c = 0; c < 4; ++c)
        z = __builtin_amdgcn_mfma_f32_32x32x16_bf16(kf[c], qf[qs][c], z, 0, 0, 0);

      // native exp2 (Q pre-scaled by 0.125*log2e) + pack pairs
      uint32_t w[8];
#pragma unroll
      for (int i = 0; i < 8; ++i) {
        float e0 = __builtin_amdgcn_exp2f(z[2 * i]);
        float e1 = __builtin_amdgcn_exp2f(z[2 * i + 1]);
        w[i] = packbf(e0, e1);
      }
      // build PV A-frags m = 0,1 via half-lane swaps
      uint32_t pf[2][4];
#pragma unroll
      for (int mm = 0; mm < 2; ++mm) {
        uint32_t a0 = w[4 * mm + 0], b0 = w[4 * mm + 2];
        uint32_t a1 = w[4 * mm + 1], b1 = w[4 * mm + 3];
        plswap(a0, b0);
        plswap(a1, b1);
        pf[mm][0] = a0;
        pf[mm][1] = a1;
        pf[mm][2] = b0;
        pf[mm][3] = b1;
      }

      // PV + l row-sums: pure MFMA cluster
      __builtin_amdgcn_s_setprio(1);
#pragma unroll
      for (int m = 0; m < 2; ++m) {
        bf16x8 pa = *(const bf16x8*)&pf[m][0];
        acc_l[qs] = __builtin_amdgcn_mfma_f32_32x32x16_bf16(pa, ones, acc_l[qs], 0, 0, 0);
#pragma unroll
        for (int ds = 0; ds < 2; ++ds)
          accO[qs][ds] = __builtin_amdgcn_mfma_f32_32x32x16_bf16(pa, vf[ds][m], accO[qs][ds], 0, 0, 0);
      }
      __builtin_amdgcn_s_setprio(0);
    }
  }

  // ---- epilogue: pair-sum the two kv-halves (wk=1 -> LDS -> wk=0 adds) ----
  __syncthreads();   // everyone done with Ks/Vs
  float* xA = (float*)&Ks[0][0];   // 16KB exchange slab for wq=0 pair
  float* xB = (float*)&Vs[0][0];   // 16KB exchange slab for wq=1 pair
  float* base = (wq == 0) ? xA : xB;
  if (wk == 1) {
#pragma unroll
    for (int qs = 0; qs < 2; ++qs)
#pragma unroll
      for (int ds = 0; ds < 2; ++ds)
        *(f32x16*)&base[((qs * 2 + ds) * 64 + lane) * 16] = accO[qs][ds];
    if (lq == 0) {
#pragma unroll
      for (int qs = 0; qs < 2; ++qs)
#pragma unroll
        for (int r = 0; r < 16; ++r) {
          int qq = (r & 3) + 8 * (r >> 2) + 4 * hi;
          lbuf[wq][qs * 32 + qq] = acc_l[qs][r];
        }
    }
  }
  __syncthreads();
  if (wk == 0) {
#pragma unroll
    for (int qs = 0; qs < 2; ++qs)
#pragma unroll
      for (int ds = 0; ds < 2; ++ds) {
        f32x16 part = *(const f32x16*)&base[((qs * 2 + ds) * 64 + lane) * 16];
#pragma unroll
        for (int r = 0; r < 16; ++r) {
          int qq = (r & 3) + 8 * (r >> 2) + 4 * hi;
          float l = acc_l[qs][r] + lbuf[wq][qs * 32 + qq];
          size_t row = (size_t)b * Ss + q0 + wq * 64 + qs * 32 + qq;
          xb[row * Dd + h * DKk + ds * 32 + lq] =
              bfbits((__bf16)((accO[qs][ds][r] + part[r]) / l));
        }
      }
  }
}

extern "C" void kernel_launch(void* const* d_in, const int* in_sizes, int n_in,
                              void* d_out, int out_size, void* d_ws, size_t ws_size,
                              hipStream_t stream) {
  const float* q  = (const float*)d_in[0];
  const float* k  = (const float*)d_in[1];
  const float* v  = (const float*)d_in[2];
  // d_in[3] = mask, faithfully ignored (reference discards masked_fill result)
  const float* Wq = (const float*)d_in[4];
  const float* bq = (const float*)d_in[5];
  const float* Wk = (const float*)d_in[6];
  const float* bk = (const float*)d_in[7];
  const float* Wv = (const float*)d_in[8];
  const float* bv = (const float*)d_in[9];
  const float* Wo = (const float*)d_in[10];
  const float* bo = (const float*)d_in[11];

  char* ws = (char*)d_ws;
  const size_t SZT = (size_t)Mm * Dd * 2;  // 16 MiB (one bf16 activation tensor)
  const size_t SZW = (size_t)Dd * Dd * 2;  // 2 MiB  (one bf16 weight tensor)
  const size_t need = 5 * SZT + 8 * SZW;   // ~96 MiB
  if (ws_size < need) return;  // fail loudly via poisoned output

  unsigned short* sh  = (unsigned short*)(ws);            // reused activation bf16
  unsigned short* sl  = (unsigned short*)(ws + SZT);      // V^T
  char* wbase = ws + 2 * SZT;
  unsigned short* Wqh = (unsigned short*)(wbase + 0 * SZW);
  unsigned short* Wql = (unsigned short*)(wbase + 1 * SZW);
  unsigned short* Wkh = (unsigned short*)(wbase + 2 * SZW);
  unsigned short* Wkl = (unsigned short*)(wbase + 3 * SZW);
  unsigned short* Wvh = (unsigned short*)(wbase + 4 * SZW);
  unsigned short* Wvl = (unsigned short*)(wbase + 5 * SZW);
  unsigned short* Woh = (unsigned short*)(wbase + 6 * SZW);
  unsigned short* Wol = (unsigned short*)(wbase + 7 * SZW);
  char* base2 = wbase + 8 * SZW;
  unsigned short* Qb = (unsigned short*)(base2 + 0 * SZT);
  unsigned short* Kb = (unsigned short*)(base2 + 1 * SZT);
  unsigned short* Vb = (unsigned short*)(base2 + 2 * SZT);
  unsigned short* VTp = sl;   // V^T lives in sl
  unsigned short* xbp = sh;   // attn output reuses sh (v-bf16 dead by then)

  const int n4t = Mm * Dd / 4;  // 2,097,152
  const int n4w = Dd * Dd / 4;  // 262,144
  const float QSCALE = 0.125f * 1.44269504f;  // 1/sqrt(d_k) * log2(e)

  // weights split (all up front)
  split_hilo<<<n4w / 256, 256, 0, stream>>>(Wq, Wqh, Wql, n4w);
  split_hilo<<<n4w / 256, 256, 0, stream>>>(Wk, Wkh, Wkl, n4w);
  split_hilo<<<n4w / 256, 256, 0, stream>>>(Wv, Wvh, Wvl, n4w);
  split_hilo<<<n4w / 256, 256, 0, stream>>>(Wo, Woh, Wol, n4w);

  // Q projection (scale folds 1/sqrt(d_k) AND log2e for exp2-softmax)
  cvt_bf16<<<n4t / 256, 256, 0, stream>>>(q, sh, n4t);
  gemm_bt<true, true><<<512, 256, 0, stream>>>(sh, Wqh, Wql, bq, Qb, Dd, Dd, QSCALE);
  // K projection
  cvt_bf16<<<n4t / 256, 256, 0, stream>>>(k, sh, n4t);
  gemm_bt<true, true><<<512, 256, 0, stream>>>(sh, Wkh, Wkl, bk, Kb, Dd, Dd, 1.0f);
  // V projection
  cvt_bf16<<<n4t / 256, 256, 0, stream>>>(v, sh, n4t);
  gemm_bt<true, true><<<512, 256, 0, stream>>>(sh, Wvh, Wvl, bv, Vb, Dd, Dd, 1.0f);

  // V^T for MFMA-friendly PV reads
  transpose_v<<<dim3(Ss / 64, Dd / 64, Bb), 256, 0, stream>>>(Vb, VTp);

  // fused attention -> x (bf16)
  attn_fused<<<1024, 256, 0, stream>>>(Qb, Kb, VTp, xbp);

  // output projection (plain bf16 is accurate enough here), fp32 out + bias
  gemm_bt<false, false><<<512, 256, 0, stream>>>(xbp, Woh, Woh, bo, d_out, Dd, Dd, 1.0f);
}

// Round 10
// 247.790 us; speedup vs baseline: 1.1522x; 1.1522x over previous
//
#include <hip/hip_runtime.h>
#include <stdint.h>

#define Bb 4
#define Ss 2048
#define Dd 1024
#define Hh 16
#define DKk 64
#define Mm (Bb * Ss)  // 8192

typedef __attribute__((ext_vector_type(4))) float f32x4;
typedef __attribute__((ext_vector_type(16))) float f32x16;
typedef __attribute__((ext_vector_type(4))) float f4v;
typedef __attribute__((ext_vector_type(8))) unsigned short us8;
typedef __attribute__((ext_vector_type(4))) unsigned short us4;
typedef __attribute__((ext_vector_type(8))) __bf16 bf16x8;

__device__ __forceinline__ unsigned short bfbits(__bf16 x) {
  union { __bf16 b; unsigned short u; } v; v.b = x; return v.u;
}
__device__ __forceinline__ uint32_t packbf(float lo, float hi) {
  union { __bf16 b[2]; uint32_t u; } v;
  v.b[0] = (__bf16)lo; v.b[1] = (__bf16)hi;
  return v.u;
}
// v_permlane32_swap_b32: a[32:63] <-> b[0:31]  (in-place, both operands)
__device__ __forceinline__ void plswap(uint32_t& a, uint32_t& b) {
  asm("v_permlane32_swap_b32 %0, %1" : "+v"(a), "+v"(b));
}
// async global->LDS, 16B per lane; LDS dest = wave-uniform base + lane*16
__device__ __forceinline__ void gl16(const unsigned short* g, unsigned short* l) {
  __builtin_amdgcn_global_load_lds(
      (__attribute__((address_space(1))) void*)(g),
      (__attribute__((address_space(3))) void*)(l), 16, 0, 0);
}

// ---------------- fp32 -> bf16 hi/lo split (Wv only) ----------------
__global__ __launch_bounds__(256)
void split_hilo(const float* __restrict__ x, unsigned short* __restrict__ hi,
                unsigned short* __restrict__ lo, int n4) {
  int i = blockIdx.x * 256 + threadIdx.x;
  if (i >= n4) return;
  f4v v = *(const f4v*)(x + (size_t)i * 4);
  us4 h, l;
#pragma unroll
  for (int j = 0; j < 4; ++j) {
    __bf16 hb = (__bf16)v[j];
    h[j] = bfbits(hb);
    l[j] = bfbits((__bf16)(v[j] - (float)hb));
  }
  *(us4*)(hi + (size_t)i * 4) = h;
  *(us4*)(lo + (size_t)i * 4) = l;
}

// ---------------- fp32 -> bf16 round (activations) ----------------
__global__ __launch_bounds__(256)
void cvt_bf16(const float* __restrict__ x, unsigned short* __restrict__ out, int n4) {
  int i = blockIdx.x * 256 + threadIdx.x;
  if (i >= n4) return;
  f4v v = *(const f4v*)(x + (size_t)i * 4);
  us4 h;
#pragma unroll
  for (int j = 0; j < 4; ++j) h[j] = bfbits((__bf16)v[j]);
  *(us4*)(out + (size_t)i * 4) = h;
}

// ---------------- fused bf16 round for 3 weight tensors ----------------
__global__ __launch_bounds__(256)
void cvt3_bf16(const float* __restrict__ x0, unsigned short* __restrict__ o0,
               const float* __restrict__ x1, unsigned short* __restrict__ o1,
               const float* __restrict__ x2, unsigned short* __restrict__ o2,
               int n4) {
  int i = blockIdx.x * 256 + threadIdx.x;
  if (i >= n4) return;
  const float* x = (blockIdx.y == 0) ? x0 : (blockIdx.y == 1) ? x1 : x2;
  unsigned short* o = (blockIdx.y == 0) ? o0 : (blockIdx.y == 1) ? o1 : o2;
  f4v v = *(const f4v*)(x + (size_t)i * 4);
  us4 h;
#pragma unroll
  for (int j = 0; j < 4; ++j) h[j] = bfbits((__bf16)v[j]);
  *(us4*)(o + (size_t)i * 4) = h;
}

// ---------------- GEMM v2: out[M,N] = A[M,K] . B[N,K]^T + bias ----------------
// m97 structure: 128x128 tile, BK=64, single-buffered LINEAR LDS staged via
// global_load_lds (pre-swizzled global source), XOR-swizzled ds_read_b128
// fragments, 2 barriers/K-step. A plain bf16; B split hi/lo if BSPLIT.
template <bool BSPLIT, bool OUT_BF16>
__global__ __launch_bounds__(256)
void gemm_bt(const unsigned short* __restrict__ A,
             const unsigned short* __restrict__ Bh, const unsigned short* __restrict__ Bl,
             const float* __restrict__ bias, void* __restrict__ outp,
             int Kdim, int Ndim, float scale) {
  __shared__ unsigned short Ath[128 * 64];
  __shared__ unsigned short Bth[128 * 64];
  __shared__ unsigned short Btl[BSPLIT ? 128 * 64 : 8];

  const int tid = threadIdx.x;
  const int wave = tid >> 6, lane = tid & 63, g = lane >> 4, ln = lane & 15;
  const int wr = wave >> 1, wc = wave & 1;
  int dd = blockIdx.x;
  int orig = (dd & 7) * 64 + (dd >> 3);   // XCD swizzle (512 = 8 * 64)
  const int bm = (orig >> 3) * 128;
  const int bn = (orig & 7) * 128;

  const int srow = lane >> 3;
  const int schunk = (lane & 7) ^ srow;

  f32x4 acc[4][4] = {};

  for (int k0 = 0; k0 < Kdim; k0 += 64) {
    __syncthreads();
#pragma unroll
    for (int ii = 0; ii < 4; ++ii) {
      const int rA = wave * 32 + ii * 8;
      gl16(&A [(size_t)(bm + rA + srow) * Kdim + k0 + schunk * 8], &Ath[rA * 64]);
      gl16(&Bh[(size_t)(bn + rA + srow) * Kdim + k0 + schunk * 8], &Bth[rA * 64]);
      if constexpr (BSPLIT) {
        gl16(&Bl[(size_t)(bn + rA + srow) * Kdim + k0 + schunk * 8], &Btl[rA * 64]);
      }
    }
    __syncthreads();

#pragma unroll
    for (int ko = 0; ko < 2; ++ko) {
      bf16x8 ah[4], bh[4], bl[4];
#pragma unroll
      for (int i = 0; i < 4; ++i) {
        const int ra = wr * 64 + i * 16 + ln;
        const int rb = wc * 64 + i * 16 + ln;
        ah[i] = *(const bf16x8*)&Ath[ra * 64 + ((ko * 4 + g) ^ (ra & 7)) * 8];
        bh[i] = *(const bf16x8*)&Bth[rb * 64 + ((ko * 4 + g) ^ (rb & 7)) * 8];
        if constexpr (BSPLIT) {
          bl[i] = *(const bf16x8*)&Btl[rb * 64 + ((ko * 4 + g) ^ (rb & 7)) * 8];
        }
      }
#pragma unroll
      for (int i = 0; i < 4; ++i)
#pragma unroll
        for (int j = 0; j < 4; ++j) {
          acc[i][j] = __builtin_amdgcn_mfma_f32_16x16x32_bf16(ah[i], bh[j], acc[i][j], 0, 0, 0);
          if constexpr (BSPLIT) {
            acc[i][j] = __builtin_amdgcn_mfma_f32_16x16x32_bf16(ah[i], bl[j], acc[i][j], 0, 0, 0);
          }
        }
    }
  }

  float bvals[4];
#pragma unroll
  for (int j = 0; j < 4; ++j) bvals[j] = bias[bn + wc * 64 + j * 16 + ln];

#pragma unroll
  for (int i = 0; i < 4; ++i) {
    int row0 = bm + wr * 64 + i * 16 + g * 4;
#pragma unroll
    for (int j = 0; j < 4; ++j) {
      int col = bn + wc * 64 + j * 16 + ln;
#pragma unroll
      for (int r = 0; r < 4; ++r) {
        float vv = (acc[i][j][r] + bvals[j]) * scale;
        if constexpr (OUT_BF16) {
          ((unsigned short*)outp)[(size_t)(row0 + r) * Ndim + col] = bfbits((__bf16)vv);
        } else {
          ((float*)outp)[(size_t)(row0 + r) * Ndim + col] = vv;
        }
      }
    }
  }
}

// ---------------- V transpose: [B,S,D] -> [B,D,S] (bf16) ----------------
__global__ __launch_bounds__(256)
void transpose_v(const unsigned short* __restrict__ Vb, unsigned short* __restrict__ VT) {
  __shared__ unsigned short tb[64 * 72];
  int s0 = blockIdx.x * 64, d0 = blockIdx.y * 64, b = blockIdx.z;
  int tid = threadIdx.x;
#pragma unroll
  for (int chi = 0; chi < 2; ++chi) {
    int c = tid + chi * 256;
    int r = c >> 3, cc = (c & 7) * 8;
    *(us8*)&tb[r * 72 + cc] = *(const us8*)&Vb[((size_t)b * Ss + s0 + r) * Dd + d0 + cc];
  }
  __syncthreads();
#pragma unroll
  for (int chi = 0; chi < 2; ++chi) {
    int c = tid + chi * 256;
    int r = c >> 3, cc = (c & 7) * 8;  // r: d row of out tile, cc: s offset
    us8 o;
#pragma unroll
    for (int j = 0; j < 8; ++j) o[j] = tb[(cc + j) * 72 + r];
    *(us8*)&VT[((size_t)b * Dd + d0 + r) * Ss + s0 + cc] = o;
  }
}

// ---------------- fused flash attention v5 (32x32x16 MFMA) ----------------
// (reverted to R8 version: QBLK=128, double-buffered gload_lds K/V, XOR
// swizzle, one barrier/tile, fixed-max softmax, native exp2, P in registers
// via permlane32_swap, l-sums on the MFMA pipe.)
__global__ __launch_bounds__(256, 4)
void attn_fused(const unsigned short* __restrict__ Qb, const unsigned short* __restrict__ Kb,
                const unsigned short* __restrict__ VT, unsigned short* __restrict__ xb) {
  __shared__ unsigned short Ks[2][64 * 64];
  __shared__ unsigned short Vs[2][64 * 64];   // V^T tile: [d][kv]

  const int tid = threadIdx.x, wave = tid >> 6, lane = tid & 63;
  const int lq = lane & 31, hi = lane >> 5;
  const int swzc = (lane & 7) ^ ((lane >> 3) & 7);  // pre-swizzled source chunk

  int dd = blockIdx.x;
  int orig = (dd & 7) * 128 + (dd >> 3);  // XCD swizzle (1024 = 8 * 128)
  const int bh = orig >> 4, qb = orig & 15;
  const int q0 = qb * 128;
  const int b = bh >> 4, h = bh & 15;

  const size_t rowBase = (size_t)b * Ss * Dd + (size_t)h * DKk;
  const size_t vtBase  = ((size_t)b * Dd + h * DKk) * Ss;

  // Q B-operand frags (once): lane holds Q[qrow][16c + 8hi + j]
  bf16x8 qf[4];
  {
    const unsigned short* qrow =
        Qb + rowBase + (size_t)(q0 + wave * 32 + lq) * Dd + 8 * hi;
#pragma unroll
    for (int c = 0; c < 4; ++c) qf[c] = *(const bf16x8*)(qrow + 16 * c);
  }

  // ones fragment for the l-row-sum MFMA
  bf16x8 ones;
#pragma unroll
  for (int j = 0; j < 8; ++j) ones[j] = (__bf16)1.0f;

  f32x16 accO[2] = {};   // [ds]
  f32x16 acc_l = {};     // row sums (replicated across cols)

  // stage tile t into buffer nb: each wave covers rows [wave*16, wave*16+16)
  // of both K and V tiles via 2+2 global_load_lds (1KB each).
  const int i0 = wave * 2;
  auto stage = [&](int t, int nb) {
#pragma unroll
    for (int ii = 0; ii < 2; ++ii) {
      const int i = i0 + ii;
      const int rr = i * 8 + (lane >> 3);
      gl16(&Kb[rowBase + (size_t)(t * 64 + rr) * Dd + swzc * 8], &Ks[nb][i * 512]);
      gl16(&VT[vtBase + (size_t)rr * Ss + t * 64 + swzc * 8], &Vs[nb][i * 512]);
    }
  };

  stage(0, 0);

  for (int t = 0; t < 32; ++t) {
    const int cur = t & 1;
    __syncthreads();   // vmcnt(0) drain -> buf[cur] ready; all done reading buf[1-cur]
    if (t + 1 < 32) stage(t + 1, 1 - cur);

    uint32_t pf[4][4];   // [m][word] PV A-frags (all indices static)
#pragma unroll
    for (int s = 0; s < 2; ++s) {
      f32x16 z = {};
#pragma unroll
      for (int c = 0; c < 4; ++c) {
        bf16x8 kf = *(const bf16x8*)
            &Ks[cur][(s * 32 + lq) * 64 + ((2 * c + hi) ^ (lq & 7)) * 8];
        z = __builtin_amdgcn_mfma_f32_32x32x16_bf16(kf, qf[c], z, 0, 0, 0);
      }
      // native exp2 (Q pre-scaled by 0.125*log2e) + pack pairs
      uint32_t w[8];
#pragma unroll
      for (int i = 0; i < 8; ++i) {
        float e0 = __builtin_amdgcn_exp2f(z[2 * i]);
        float e1 = __builtin_amdgcn_exp2f(z[2 * i + 1]);
        w[i] = packbf(e0, e1);
      }
      // build PV A-frags m = 2s, 2s+1 via half-lane swaps
#pragma unroll
      for (int mm = 0; mm < 2; ++mm) {
        uint32_t a0 = w[4 * mm + 0], b0 = w[4 * mm + 2];
        uint32_t a1 = w[4 * mm + 1], b1 = w[4 * mm + 3];
        plswap(a0, b0);
        plswap(a1, b1);
        pf[2 * s + mm][0] = a0;
        pf[2 * s + mm][1] = a1;
        pf[2 * s + mm][2] = b0;
        pf[2 * s + mm][3] = b1;
      }
    }

    // PV + l row-sums: pure MFMA cluster
    __builtin_amdgcn_s_setprio(1);
#pragma unroll
    for (int m = 0; m < 4; ++m) {
      bf16x8 pa = *(const bf16x8*)&pf[m][0];
      acc_l = __builtin_amdgcn_mfma_f32_32x32x16_bf16(pa, ones, acc_l, 0, 0, 0);
#pragma unroll
      for (int ds = 0; ds < 2; ++ds) {
        bf16x8 bv = *(const bf16x8*)
            &Vs[cur][(ds * 32 + lq) * 64 + ((2 * m + hi) ^ (lq & 7)) * 8];
        accO[ds] = __builtin_amdgcn_mfma_f32_32x32x16_bf16(pa, bv, accO[ds], 0, 0, 0);
      }
    }
    __builtin_amdgcn_s_setprio(0);
  }

  // epilogue: acc_l rows align with accO rows (row = (r&3)+8*(r>>2)+4*hi)
#pragma unroll
  for (int ds = 0; ds < 2; ++ds)
#pragma unroll
    for (int r = 0; r < 16; ++r) {
      int q = (r & 3) + 8 * (r >> 2) + 4 * hi;
      size_t row = (size_t)b * Ss + q0 + wave * 32 + q;
      xb[row * Dd + h * DKk + ds * 32 + lq] =
          bfbits((__bf16)(accO[ds][r] / acc_l[r]));
    }
}

extern "C" void kernel_launch(void* const* d_in, const int* in_sizes, int n_in,
                              void* d_out, int out_size, void* d_ws, size_t ws_size,
                              hipStream_t stream) {
  const float* q  = (const float*)d_in[0];
  const float* k  = (const float*)d_in[1];
  const float* v  = (const float*)d_in[2];
  // d_in[3] = mask, faithfully ignored (reference discards masked_fill result)
  const float* Wq = (const float*)d_in[4];
  const float* bq = (const float*)d_in[5];
  const float* Wk = (const float*)d_in[6];
  const float* bk = (const float*)d_in[7];
  const float* Wv = (const float*)d_in[8];
  const float* bv = (const float*)d_in[9];
  const float* Wo = (const float*)d_in[10];
  const float* bo = (const float*)d_in[11];

  char* ws = (char*)d_ws;
  const size_t SZT = (size_t)Mm * Dd * 2;  // 16 MiB (one bf16 activation tensor)
  const size_t SZW = (size_t)Dd * Dd * 2;  // 2 MiB  (one bf16 weight tensor)
  const size_t need = 5 * SZT + 8 * SZW;   // ~96 MiB
  if (ws_size < need) return;  // fail loudly via poisoned output

  unsigned short* sh  = (unsigned short*)(ws);            // reused activation bf16
  unsigned short* sl  = (unsigned short*)(ws + SZT);      // V^T
  char* wbase = ws + 2 * SZT;
  unsigned short* Wqh = (unsigned short*)(wbase + 0 * SZW);
  unsigned short* Wkh = (unsigned short*)(wbase + 2 * SZW);
  unsigned short* Wvh = (unsigned short*)(wbase + 4 * SZW);
  unsigned short* Wvl = (unsigned short*)(wbase + 5 * SZW);
  unsigned short* Woh = (unsigned short*)(wbase + 6 * SZW);
  char* base2 = wbase + 8 * SZW;
  unsigned short* Qb = (unsigned short*)(base2 + 0 * SZT);
  unsigned short* Kb = (unsigned short*)(base2 + 1 * SZT);
  unsigned short* Vb = (unsigned short*)(base2 + 2 * SZT);
  unsigned short* VTp = sl;   // V^T lives in sl
  unsigned short* xbp = sh;   // attn output reuses sh (v-bf16 dead by then)

  const int n4t = Mm * Dd / 4;  // 2,097,152
  const int n4w = Dd * Dd / 4;  // 262,144
  const float QSCALE = 0.125f * 1.44269504f;  // 1/sqrt(d_k) * log2(e)

  // weight prep: Wq/Wk/Wo plain bf16 (error budget allows it); Wv split
  cvt3_bf16<<<dim3(n4w / 256, 3), 256, 0, stream>>>(Wq, Wqh, Wk, Wkh, Wo, Woh, n4w);
  split_hilo<<<n4w / 256, 256, 0, stream>>>(Wv, Wvh, Wvl, n4w);

  // Q projection (scale folds 1/sqrt(d_k) AND log2e for exp2-softmax)
  cvt_bf16<<<n4t / 256, 256, 0, stream>>>(q, sh, n4t);
  gemm_bt<false, true><<<512, 256, 0, stream>>>(sh, Wqh, Wqh, bq, Qb, Dd, Dd, QSCALE);
  // K projection
  cvt_bf16<<<n4t / 256, 256, 0, stream>>>(k, sh, n4t);
  gemm_bt<false, true><<<512, 256, 0, stream>>>(sh, Wkh, Wkh, bk, Kb, Dd, Dd, 1.0f);
  // V projection (keep split: V errors pass straight to the output)
  cvt_bf16<<<n4t / 256, 256, 0, stream>>>(v, sh, n4t);
  gemm_bt<true, true><<<512, 256, 0, stream>>>(sh, Wvh, Wvl, bv, Vb, Dd, Dd, 1.0f);

  // V^T for MFMA-friendly PV reads
  transpose_v<<<dim3(Ss / 64, Dd / 64, Bb), 256, 0, stream>>>(Vb, VTp);

  // fused attention -> x (bf16)
  attn_fused<<<1024, 256, 0, stream>>>(Qb, Kb, VTp, xbp);

  // output projection (plain bf16), fp32 out + bias
  gemm_bt<false, false><<<512, 256, 0, stream>>>(xbp, Woh, Woh, bo, d_out, Dd, Dd, 1.0f);
}

// Round 11
// 236.963 us; speedup vs baseline: 1.2048x; 1.0457x over previous
//
#include <hip/hip_runtime.h>
#include <stdint.h>

#define Bb 4
#define Ss 2048
#define Dd 1024
#define Hh 16
#define DKk 64
#define Mm (Bb * Ss)  // 8192

typedef __attribute__((ext_vector_type(4))) float f32x4;
typedef __attribute__((ext_vector_type(16))) float f32x16;
typedef __attribute__((ext_vector_type(4))) float f4v;
typedef __attribute__((ext_vector_type(8))) unsigned short us8;
typedef __attribute__((ext_vector_type(4))) unsigned short us4;
typedef __attribute__((ext_vector_type(8))) __bf16 bf16x8;

__device__ __forceinline__ unsigned short bfbits(__bf16 x) {
  union { __bf16 b; unsigned short u; } v; v.b = x; return v.u;
}
__device__ __forceinline__ uint32_t packbf(float lo, float hi) {
  union { __bf16 b[2]; uint32_t u; } v;
  v.b[0] = (__bf16)lo; v.b[1] = (__bf16)hi;
  return v.u;
}
// v_permlane32_swap_b32: a[32:63] <-> b[0:31]  (in-place, both operands)
__device__ __forceinline__ void plswap(uint32_t& a, uint32_t& b) {
  asm("v_permlane32_swap_b32 %0, %1" : "+v"(a), "+v"(b));
}
// async global->LDS, 16B per lane; LDS dest = wave-uniform base + lane*16
__device__ __forceinline__ void gl16(const unsigned short* g, unsigned short* l) {
  __builtin_amdgcn_global_load_lds(
      (__attribute__((address_space(1))) void*)(g),
      (__attribute__((address_space(3))) void*)(l), 16, 0, 0);
}

// ---------------- fp32 -> bf16 hi/lo split (Wv only) ----------------
__global__ __launch_bounds__(256)
void split_hilo(const float* __restrict__ x, unsigned short* __restrict__ hi,
                unsigned short* __restrict__ lo, int n4) {
  int i = blockIdx.x * 256 + threadIdx.x;
  if (i >= n4) return;
  f4v v = *(const f4v*)(x + (size_t)i * 4);
  us4 h, l;
#pragma unroll
  for (int j = 0; j < 4; ++j) {
    __bf16 hb = (__bf16)v[j];
    h[j] = bfbits(hb);
    l[j] = bfbits((__bf16)(v[j] - (float)hb));
  }
  *(us4*)(hi + (size_t)i * 4) = h;
  *(us4*)(lo + (size_t)i * 4) = l;
}

// ---------------- fused bf16 round for 3 tensors (weights or activations) ----
__global__ __launch_bounds__(256)
void cvt3_bf16(const float* __restrict__ x0, unsigned short* __restrict__ o0,
               const float* __restrict__ x1, unsigned short* __restrict__ o1,
               const float* __restrict__ x2, unsigned short* __restrict__ o2,
               int n4) {
  int i = blockIdx.x * 256 + threadIdx.x;
  if (i >= n4) return;
  const float* x = (blockIdx.y == 0) ? x0 : (blockIdx.y == 1) ? x1 : x2;
  unsigned short* o = (blockIdx.y == 0) ? o0 : (blockIdx.y == 1) ? o1 : o2;
  f4v v = *(const f4v*)(x + (size_t)i * 4);
  us4 h;
#pragma unroll
  for (int j = 0; j < 4; ++j) h[j] = bfbits((__bf16)v[j]);
  *(us4*)(o + (size_t)i * 4) = h;
}

// ---------------- GEMM v2: out[M,N] = A[M,K] . B[N,K]^T + bias ----------------
// m97 structure: 128x128 tile, BK=64, single-buffered LINEAR LDS staged via
// global_load_lds (pre-swizzled global source), XOR-swizzled ds_read_b128
// fragments, 2 barriers/K-step. A plain bf16; B split hi/lo if BSPLIT.
template <bool BSPLIT, bool OUT_BF16>
__global__ __launch_bounds__(256)
void gemm_bt(const unsigned short* __restrict__ A,
             const unsigned short* __restrict__ Bh, const unsigned short* __restrict__ Bl,
             const float* __restrict__ bias, void* __restrict__ outp,
             int Kdim, int Ndim, float scale) {
  __shared__ unsigned short Ath[128 * 64];
  __shared__ unsigned short Bth[128 * 64];
  __shared__ unsigned short Btl[BSPLIT ? 128 * 64 : 8];

  const int tid = threadIdx.x;
  const int wave = tid >> 6, lane = tid & 63, g = lane >> 4, ln = lane & 15;
  const int wr = wave >> 1, wc = wave & 1;
  int dd = blockIdx.x;
  int orig = (dd & 7) * 64 + (dd >> 3);   // XCD swizzle (512 = 8 * 64)
  const int bm = (orig >> 3) * 128;
  const int bn = (orig & 7) * 128;

  const int srow = lane >> 3;
  const int schunk = (lane & 7) ^ srow;

  f32x4 acc[4][4] = {};

  for (int k0 = 0; k0 < Kdim; k0 += 64) {
    __syncthreads();
#pragma unroll
    for (int ii = 0; ii < 4; ++ii) {
      const int rA = wave * 32 + ii * 8;
      gl16(&A [(size_t)(bm + rA + srow) * Kdim + k0 + schunk * 8], &Ath[rA * 64]);
      gl16(&Bh[(size_t)(bn + rA + srow) * Kdim + k0 + schunk * 8], &Bth[rA * 64]);
      if constexpr (BSPLIT) {
        gl16(&Bl[(size_t)(bn + rA + srow) * Kdim + k0 + schunk * 8], &Btl[rA * 64]);
      }
    }
    __syncthreads();

#pragma unroll
    for (int ko = 0; ko < 2; ++ko) {
      bf16x8 ah[4], bh[4], bl[4];
#pragma unroll
      for (int i = 0; i < 4; ++i) {
        const int ra = wr * 64 + i * 16 + ln;
        const int rb = wc * 64 + i * 16 + ln;
        ah[i] = *(const bf16x8*)&Ath[ra * 64 + ((ko * 4 + g) ^ (ra & 7)) * 8];
        bh[i] = *(const bf16x8*)&Bth[rb * 64 + ((ko * 4 + g) ^ (rb & 7)) * 8];
        if constexpr (BSPLIT) {
          bl[i] = *(const bf16x8*)&Btl[rb * 64 + ((ko * 4 + g) ^ (rb & 7)) * 8];
        }
      }
#pragma unroll
      for (int i = 0; i < 4; ++i)
#pragma unroll
        for (int j = 0; j < 4; ++j) {
          acc[i][j] = __builtin_amdgcn_mfma_f32_16x16x32_bf16(ah[i], bh[j], acc[i][j], 0, 0, 0);
          if constexpr (BSPLIT) {
            acc[i][j] = __builtin_amdgcn_mfma_f32_16x16x32_bf16(ah[i], bl[j], acc[i][j], 0, 0, 0);
          }
        }
    }
  }

  float bvals[4];
#pragma unroll
  for (int j = 0; j < 4; ++j) bvals[j] = bias[bn + wc * 64 + j * 16 + ln];

#pragma unroll
  for (int i = 0; i < 4; ++i) {
    int row0 = bm + wr * 64 + i * 16 + g * 4;
#pragma unroll
    for (int j = 0; j < 4; ++j) {
      int col = bn + wc * 64 + j * 16 + ln;
#pragma unroll
      for (int r = 0; r < 4; ++r) {
        float vv = (acc[i][j][r] + bvals[j]) * scale;
        if constexpr (OUT_BF16) {
          ((unsigned short*)outp)[(size_t)(row0 + r) * Ndim + col] = bfbits((__bf16)vv);
        } else {
          ((float*)outp)[(size_t)(row0 + r) * Ndim + col] = vv;
        }
      }
    }
  }
}

// ---------------- V-projection GEMM with fused transposed output ----------
// Same m97 body (BSPLIT=true), but epilogue routes the 128x128 tile through
// the dead staging LDS (stride 132: ds_write_b64 at 2-way aliasing) and
// stores VT[B, D, S] directly with coalesced us8 writes. Kills the separate
// transpose kernel and one 16MB read + 16MB write.
__global__ __launch_bounds__(256)
void gemm_vT(const unsigned short* __restrict__ A,
             const unsigned short* __restrict__ Bh, const unsigned short* __restrict__ Bl,
             const float* __restrict__ bias, unsigned short* __restrict__ VT,
             int Kdim, int Ndim) {
  __shared__ unsigned short S[3 * 128 * 64];   // staging; reused as T[128][132]
  unsigned short* Ath = S;
  unsigned short* Bth = S + 8192;
  unsigned short* Btl = S + 16384;

  const int tid = threadIdx.x;
  const int wave = tid >> 6, lane = tid & 63, g = lane >> 4, ln = lane & 15;
  const int wr = wave >> 1, wc = wave & 1;
  int dd = blockIdx.x;
  int orig = (dd & 7) * 64 + (dd >> 3);   // XCD swizzle (512 = 8 * 64)
  const int bm = (orig >> 3) * 128;
  const int bn = (orig & 7) * 128;

  const int srow = lane >> 3;
  const int schunk = (lane & 7) ^ srow;

  f32x4 acc[4][4] = {};

  for (int k0 = 0; k0 < Kdim; k0 += 64) {
    __syncthreads();
#pragma unroll
    for (int ii = 0; ii < 4; ++ii) {
      const int rA = wave * 32 + ii * 8;
      gl16(&A [(size_t)(bm + rA + srow) * Kdim + k0 + schunk * 8], &Ath[rA * 64]);
      gl16(&Bh[(size_t)(bn + rA + srow) * Kdim + k0 + schunk * 8], &Bth[rA * 64]);
      gl16(&Bl[(size_t)(bn + rA + srow) * Kdim + k0 + schunk * 8], &Btl[rA * 64]);
    }
    __syncthreads();

#pragma unroll
    for (int ko = 0; ko < 2; ++ko) {
      bf16x8 ah[4], bh[4], bl[4];
#pragma unroll
      for (int i = 0; i < 4; ++i) {
        const int ra = wr * 64 + i * 16 + ln;
        const int rb = wc * 64 + i * 16 + ln;
        ah[i] = *(const bf16x8*)&Ath[ra * 64 + ((ko * 4 + g) ^ (ra & 7)) * 8];
        bh[i] = *(const bf16x8*)&Bth[rb * 64 + ((ko * 4 + g) ^ (rb & 7)) * 8];
        bl[i] = *(const bf16x8*)&Btl[rb * 64 + ((ko * 4 + g) ^ (rb & 7)) * 8];
      }
#pragma unroll
      for (int i = 0; i < 4; ++i)
#pragma unroll
        for (int j = 0; j < 4; ++j) {
          acc[i][j] = __builtin_amdgcn_mfma_f32_16x16x32_bf16(ah[i], bh[j], acc[i][j], 0, 0, 0);
          acc[i][j] = __builtin_amdgcn_mfma_f32_16x16x32_bf16(ah[i], bl[j], acc[i][j], 0, 0, 0);
        }
    }
  }

  float bvals[4];
#pragma unroll
  for (int j = 0; j < 4; ++j) bvals[j] = bias[bn + wc * 64 + j * 16 + ln];

  __syncthreads();   // staging LDS now dead; safe to reuse as T
  // T[d_local][s_local], stride 132 shorts; write 4 consecutive s per us4
#pragma unroll
  for (int i = 0; i < 4; ++i) {
    int sl0 = wr * 64 + i * 16 + g * 4;
#pragma unroll
    for (int j = 0; j < 4; ++j) {
      int dl = wc * 64 + j * 16 + ln;
      us4 w;
#pragma unroll
      for (int r = 0; r < 4; ++r) w[r] = bfbits((__bf16)(acc[i][j][r] + bvals[j]));
      *(us4*)&S[dl * 132 + sl0] = w;
    }
  }
  __syncthreads();

  const int bb = bm >> 11, s0g = bm & 2047;
#pragma unroll
  for (int it = 0; it < 8; ++it) {
    int u = it * 256 + tid;          // 128 d x 16 s-chunks of 8
    int dl = u >> 4, sc = (u & 15) * 8;
    us8 o = *(const us8*)&S[dl * 132 + sc];
    *(us8*)&VT[((size_t)bb * Dd + bn + dl) * Ss + s0g + sc] = o;
  }
}

// ---------------- fused flash attention v5 (32x32x16 MFMA) ----------------
// (unchanged: QBLK=128, double-buffered gload_lds K/V, XOR swizzle, one
// barrier/tile, fixed-max softmax, native exp2, P in registers via
// permlane32_swap, l-sums on the MFMA pipe.)
__global__ __launch_bounds__(256, 4)
void attn_fused(const unsigned short* __restrict__ Qb, const unsigned short* __restrict__ Kb,
                const unsigned short* __restrict__ VT, unsigned short* __restrict__ xb) {
  __shared__ unsigned short Ks[2][64 * 64];
  __shared__ unsigned short Vs[2][64 * 64];   // V^T tile: [d][kv]

  const int tid = threadIdx.x, wave = tid >> 6, lane = tid & 63;
  const int lq = lane & 31, hi = lane >> 5;
  const int swzc = (lane & 7) ^ ((lane >> 3) & 7);  // pre-swizzled source chunk

  int dd = blockIdx.x;
  int orig = (dd & 7) * 128 + (dd >> 3);  // XCD swizzle (1024 = 8 * 128)
  const int bh = orig >> 4, qb = orig & 15;
  const int q0 = qb * 128;
  const int b = bh >> 4, h = bh & 15;

  const size_t rowBase = (size_t)b * Ss * Dd + (size_t)h * DKk;
  const size_t vtBase  = ((size_t)b * Dd + h * DKk) * Ss;

  // Q B-operand frags (once): lane holds Q[qrow][16c + 8hi + j]
  bf16x8 qf[4];
  {
    const unsigned short* qrow =
        Qb + rowBase + (size_t)(q0 + wave * 32 + lq) * Dd + 8 * hi;
#pragma unroll
    for (int c = 0; c < 4; ++c) qf[c] = *(const bf16x8*)(qrow + 16 * c);
  }

  // ones fragment for the l-row-sum MFMA
  bf16x8 ones;
#pragma unroll
  for (int j = 0; j < 8; ++j) ones[j] = (__bf16)1.0f;

  f32x16 accO[2] = {};   // [ds]
  f32x16 acc_l = {};     // row sums (replicated across cols)

  // stage tile t into buffer nb: each wave covers rows [wave*16, wave*16+16)
  // of both K and V tiles via 2+2 global_load_lds (1KB each).
  const int i0 = wave * 2;
  auto stage = [&](int t, int nb) {
#pragma unroll
    for (int ii = 0; ii < 2; ++ii) {
      const int i = i0 + ii;
      const int rr = i * 8 + (lane >> 3);
      gl16(&Kb[rowBase + (size_t)(t * 64 + rr) * Dd + swzc * 8], &Ks[nb][i * 512]);
      gl16(&VT[vtBase + (size_t)rr * Ss + t * 64 + swzc * 8], &Vs[nb][i * 512]);
    }
  };

  stage(0, 0);

  for (int t = 0; t < 32; ++t) {
    const int cur = t & 1;
    __syncthreads();   // vmcnt(0) drain -> buf[cur] ready; all done reading buf[1-cur]
    if (t + 1 < 32) stage(t + 1, 1 - cur);

    uint32_t pf[4][4];   // [m][word] PV A-frags (all indices static)
#pragma unroll
    for (int s = 0; s < 2; ++s) {
      f32x16 z = {};
#pragma unroll
      for (int c = 0; c < 4; ++c) {
        bf16x8 kf = *(const bf16x8*)
            &Ks[cur][(s * 32 + lq) * 64 + ((2 * c + hi) ^ (lq & 7)) * 8];
        z = __builtin_amdgcn_mfma_f32_32x32x16_bf16(kf, qf[c], z, 0, 0, 0);
      }
      // native exp2 (Q pre-scaled by 0.125*log2e) + pack pairs
      uint32_t w[8];
#pragma unroll
      for (int i = 0; i < 8; ++i) {
        float e0 = __builtin_amdgcn_exp2f(z[2 * i]);
        float e1 = __builtin_amdgcn_exp2f(z[2 * i + 1]);
        w[i] = packbf(e0, e1);
      }
      // build PV A-frags m = 2s, 2s+1 via half-lane swaps
#pragma unroll
      for (int mm = 0; mm < 2; ++mm) {
        uint32_t a0 = w[4 * mm + 0], b0 = w[4 * mm + 2];
        uint32_t a1 = w[4 * mm + 1], b1 = w[4 * mm + 3];
        plswap(a0, b0);
        plswap(a1, b1);
        pf[2 * s + mm][0] = a0;
        pf[2 * s + mm][1] = a1;
        pf[2 * s + mm][2] = b0;
        pf[2 * s + mm][3] = b1;
      }
    }

    // PV + l row-sums: pure MFMA cluster
    __builtin_amdgcn_s_setprio(1);
#pragma unroll
    for (int m = 0; m < 4; ++m) {
      bf16x8 pa = *(const bf16x8*)&pf[m][0];
      acc_l = __builtin_amdgcn_mfma_f32_32x32x16_bf16(pa, ones, acc_l, 0, 0, 0);
#pragma unroll
      for (int ds = 0; ds < 2; ++ds) {
        bf16x8 bv = *(const bf16x8*)
            &Vs[cur][(ds * 32 + lq) * 64 + ((2 * m + hi) ^ (lq & 7)) * 8];
        accO[ds] = __builtin_amdgcn_mfma_f32_32x32x16_bf16(pa, bv, accO[ds], 0, 0, 0);
      }
    }
    __builtin_amdgcn_s_setprio(0);
  }

  // epilogue: acc_l rows align with accO rows (row = (r&3)+8*(r>>2)+4*hi)
#pragma unroll
  for (int ds = 0; ds < 2; ++ds)
#pragma unroll
    for (int r = 0; r < 16; ++r) {
      int q = (r & 3) + 8 * (r >> 2) + 4 * hi;
      size_t row = (size_t)b * Ss + q0 + wave * 32 + q;
      xb[row * Dd + h * DKk + ds * 32 + lq] =
          bfbits((__bf16)(accO[ds][r] / acc_l[r]));
    }
}

extern "C" void kernel_launch(void* const* d_in, const int* in_sizes, int n_in,
                              void* d_out, int out_size, void* d_ws, size_t ws_size,
                              hipStream_t stream) {
  const float* q  = (const float*)d_in[0];
  const float* k  = (const float*)d_in[1];
  const float* v  = (const float*)d_in[2];
  // d_in[3] = mask, faithfully ignored (reference discards masked_fill result)
  const float* Wq = (const float*)d_in[4];
  const float* bq = (const float*)d_in[5];
  const float* Wk = (const float*)d_in[6];
  const float* bk = (const float*)d_in[7];
  const float* Wv = (const float*)d_in[8];
  const float* bv = (const float*)d_in[9];
  const float* Wo = (const float*)d_in[10];
  const float* bo = (const float*)d_in[11];

  char* ws = (char*)d_ws;
  const size_t SZT = (size_t)Mm * Dd * 2;  // 16 MiB (one bf16 activation tensor)
  const size_t SZW = (size_t)Dd * Dd * 2;  // 2 MiB  (one bf16 weight tensor)
  const size_t need = 5 * SZT + 8 * SZW;   // ~96 MiB
  if (ws_size < need) return;  // fail loudly via poisoned output

  unsigned short* ab_q = (unsigned short*)(ws + 0 * SZT);  // q bf16; later VT
  unsigned short* ab_k = (unsigned short*)(ws + 1 * SZT);  // k bf16; later xb
  unsigned short* ab_v = (unsigned short*)(ws + 2 * SZT);  // v bf16
  char* wbase = ws + 3 * SZT;
  unsigned short* Wqh = (unsigned short*)(wbase + 0 * SZW);
  unsigned short* Wkh = (unsigned short*)(wbase + 1 * SZW);
  unsigned short* Wvh = (unsigned short*)(wbase + 2 * SZW);
  unsigned short* Wvl = (unsigned short*)(wbase + 3 * SZW);
  unsigned short* Woh = (unsigned short*)(wbase + 4 * SZW);
  char* base2 = wbase + 8 * SZW;
  unsigned short* Qb = (unsigned short*)(base2 + 0 * SZT);
  unsigned short* Kb = (unsigned short*)(base2 + 1 * SZT);
  unsigned short* VTp = ab_q;  // dead after Q-GEMM, written by gemm_vT
  unsigned short* xbp = ab_k;  // dead after K-GEMM, written by attn

  const int n4t = Mm * Dd / 4;  // 2,097,152
  const int n4w = Dd * Dd / 4;  // 262,144
  const float QSCALE = 0.125f * 1.44269504f;  // 1/sqrt(d_k) * log2(e)

  // weight prep: Wq/Wk/Wo plain bf16; Wv hi/lo split
  cvt3_bf16<<<dim3(n4w / 256, 3), 256, 0, stream>>>(Wq, Wqh, Wk, Wkh, Wo, Woh, n4w);
  split_hilo<<<n4w / 256, 256, 0, stream>>>(Wv, Wvh, Wvl, n4w);

  // all three activations -> bf16 in one launch
  cvt3_bf16<<<dim3(n4t / 256, 3), 256, 0, stream>>>(q, ab_q, k, ab_k, v, ab_v, n4t);

  // Q projection (scale folds 1/sqrt(d_k) AND log2e for exp2-softmax)
  gemm_bt<false, true><<<512, 256, 0, stream>>>(ab_q, Wqh, Wqh, bq, Qb, Dd, Dd, QSCALE);
  // K projection
  gemm_bt<false, true><<<512, 256, 0, stream>>>(ab_k, Wkh, Wkh, bk, Kb, Dd, Dd, 1.0f);
  // V projection with fused transpose -> VT (split weights: V errors pass to output)
  gemm_vT<<<512, 256, 0, stream>>>(ab_v, Wvh, Wvl, bv, VTp, Dd, Dd);

  // fused attention -> x (bf16)
  attn_fused<<<1024, 256, 0, stream>>>(Qb, Kb, VTp, xbp);

  // output projection (plain bf16), fp32 out + bias
  gemm_bt<false, false><<<512, 256, 0, stream>>>(xbp, Woh, Woh, bo, d_out, Dd, Dd, 1.0f);
}

// Round 12
// 228.634 us; speedup vs baseline: 1.2487x; 1.0364x over previous
//
#include <hip/hip_runtime.h>
#include <stdint.h>

#define Bb 4
#define Ss 2048
#define Dd 1024
#define Hh 16
#define DKk 64
#define Mm (Bb * Ss)  // 8192

typedef __attribute__((ext_vector_type(4))) float f32x4;
typedef __attribute__((ext_vector_type(16))) float f32x16;
typedef __attribute__((ext_vector_type(4))) float f4v;
typedef __attribute__((ext_vector_type(8))) unsigned short us8;
typedef __attribute__((ext_vector_type(4))) unsigned short us4;
typedef __attribute__((ext_vector_type(8))) __bf16 bf16x8;

__device__ __forceinline__ unsigned short bfbits(__bf16 x) {
  union { __bf16 b; unsigned short u; } v; v.b = x; return v.u;
}
__device__ __forceinline__ uint32_t packbf(float lo, float hi) {
  union { __bf16 b[2]; uint32_t u; } v;
  v.b[0] = (__bf16)lo; v.b[1] = (__bf16)hi;
  return v.u;
}
// v_permlane32_swap_b32: a[32:63] <-> b[0:31]  (in-place, both operands)
__device__ __forceinline__ void plswap(uint32_t& a, uint32_t& b) {
  asm("v_permlane32_swap_b32 %0, %1" : "+v"(a), "+v"(b));
}
// async global->LDS, 16B per lane; LDS dest = wave-uniform base + lane*16
__device__ __forceinline__ void gl16(const unsigned short* g, unsigned short* l) {
  __builtin_amdgcn_global_load_lds(
      (__attribute__((address_space(1))) void*)(g),
      (__attribute__((address_space(3))) void*)(l), 16, 0, 0);
}

// ---------------- fused weight prep: cvt Wq/Wk/Wo + split Wv ----------------
__global__ __launch_bounds__(256)
void wprep(const float* __restrict__ Wq, unsigned short* __restrict__ oq,
           const float* __restrict__ Wk, unsigned short* __restrict__ ok,
           const float* __restrict__ Wo, unsigned short* __restrict__ oo,
           const float* __restrict__ Wv, unsigned short* __restrict__ vh,
           unsigned short* __restrict__ vl, int n4) {
  int i = blockIdx.x * 256 + threadIdx.x;
  if (i >= n4) return;
  int which = blockIdx.y;
  if (which < 3) {
    const float* x = (which == 0) ? Wq : (which == 1) ? Wk : Wo;
    unsigned short* o = (which == 0) ? oq : (which == 1) ? ok : oo;
    f4v v = *(const f4v*)(x + (size_t)i * 4);
    us4 h;
#pragma unroll
    for (int j = 0; j < 4; ++j) h[j] = bfbits((__bf16)v[j]);
    *(us4*)(o + (size_t)i * 4) = h;
  } else {
    f4v v = *(const f4v*)(Wv + (size_t)i * 4);
    us4 h, l;
#pragma unroll
    for (int j = 0; j < 4; ++j) {
      __bf16 hb = (__bf16)v[j];
      h[j] = bfbits(hb);
      l[j] = bfbits((__bf16)(v[j] - (float)hb));
    }
    *(us4*)(vh + (size_t)i * 4) = h;
    *(us4*)(vl + (size_t)i * 4) = l;
  }
}

// ---------------- fused bf16 round for 3 activation tensors ----------------
__global__ __launch_bounds__(256)
void cvt3_bf16(const float* __restrict__ x0, unsigned short* __restrict__ o0,
               const float* __restrict__ x1, unsigned short* __restrict__ o1,
               const float* __restrict__ x2, unsigned short* __restrict__ o2,
               int n4) {
  int i = blockIdx.x * 256 + threadIdx.x;
  if (i >= n4) return;
  const float* x = (blockIdx.y == 0) ? x0 : (blockIdx.y == 1) ? x1 : x2;
  unsigned short* o = (blockIdx.y == 0) ? o0 : (blockIdx.y == 1) ? o1 : o2;
  f4v v = *(const f4v*)(x + (size_t)i * 4);
  us4 h;
#pragma unroll
  for (int j = 0; j < 4; ++j) h[j] = bfbits((__bf16)v[j]);
  *(us4*)(o + (size_t)i * 4) = h;
}

// ---------------- fused Q+K projection GEMM ----------------
// Two independent 512-block GEMMs in one 1024-block launch -> 4 blocks/CU
// (was 2). XCD swizzle: orig<512 = Q on XCDs 0-3, K on XCDs 4-7; per-XCD
// working set stays ~4MB (L2-fit). m97 body: 128x128, BK=64, gload_lds,
// XOR-swizzled ds_read_b128.
__global__ __launch_bounds__(256)
void gemm_qk(const unsigned short* __restrict__ Aq, const unsigned short* __restrict__ Ak,
             const unsigned short* __restrict__ Wqh, const unsigned short* __restrict__ Wkh,
             const float* __restrict__ bq, const float* __restrict__ bk,
             unsigned short* __restrict__ Qb, unsigned short* __restrict__ Kb,
             float qscale) {
  __shared__ unsigned short Ath[128 * 64];
  __shared__ unsigned short Bth[128 * 64];

  const int tid = threadIdx.x;
  const int wave = tid >> 6, lane = tid & 63, g = lane >> 4, ln = lane & 15;
  const int wr = wave >> 1, wc = wave & 1;
  int dd = blockIdx.x;
  int orig = (dd & 7) * 128 + (dd >> 3);   // XCD swizzle (1024 = 8 * 128)
  const int op = orig >> 9;                // 0 = Q, 1 = K
  const int rem = orig & 511;
  const int bm = (rem >> 3) * 128;
  const int bn = (rem & 7) * 128;

  const unsigned short* A  = op ? Ak : Aq;
  const unsigned short* Bh = op ? Wkh : Wqh;
  const float* bias        = op ? bk : bq;
  unsigned short* outp     = op ? Kb : Qb;
  const float scale        = op ? 1.0f : qscale;

  const int srow = lane >> 3;
  const int schunk = (lane & 7) ^ srow;

  f32x4 acc[4][4] = {};

  for (int k0 = 0; k0 < Dd; k0 += 64) {
    __syncthreads();
#pragma unroll
    for (int ii = 0; ii < 4; ++ii) {
      const int rA = wave * 32 + ii * 8;
      gl16(&A [(size_t)(bm + rA + srow) * Dd + k0 + schunk * 8], &Ath[rA * 64]);
      gl16(&Bh[(size_t)(bn + rA + srow) * Dd + k0 + schunk * 8], &Bth[rA * 64]);
    }
    __syncthreads();

#pragma unroll
    for (int ko = 0; ko < 2; ++ko) {
      bf16x8 ah[4], bh[4];
#pragma unroll
      for (int i = 0; i < 4; ++i) {
        const int ra = wr * 64 + i * 16 + ln;
        const int rb = wc * 64 + i * 16 + ln;
        ah[i] = *(const bf16x8*)&Ath[ra * 64 + ((ko * 4 + g) ^ (ra & 7)) * 8];
        bh[i] = *(const bf16x8*)&Bth[rb * 64 + ((ko * 4 + g) ^ (rb & 7)) * 8];
      }
#pragma unroll
      for (int i = 0; i < 4; ++i)
#pragma unroll
        for (int j = 0; j < 4; ++j)
          acc[i][j] = __builtin_amdgcn_mfma_f32_16x16x32_bf16(ah[i], bh[j], acc[i][j], 0, 0, 0);
    }
  }

  float bvals[4];
#pragma unroll
  for (int j = 0; j < 4; ++j) bvals[j] = bias[bn + wc * 64 + j * 16 + ln];

#pragma unroll
  for (int i = 0; i < 4; ++i) {
    int row0 = bm + wr * 64 + i * 16 + g * 4;
#pragma unroll
    for (int j = 0; j < 4; ++j) {
      int col = bn + wc * 64 + j * 16 + ln;
#pragma unroll
      for (int r = 0; r < 4; ++r) {
        float vv = (acc[i][j][r] + bvals[j]) * scale;
        outp[(size_t)(row0 + r) * Dd + col] = bfbits((__bf16)vv);
      }
    }
  }
}

// ---------------- GEMM v2 (Wo): out[M,N] = A[M,K] . B[N,K]^T + bias --------
template <bool BSPLIT, bool OUT_BF16>
__global__ __launch_bounds__(256)
void gemm_bt(const unsigned short* __restrict__ A,
             const unsigned short* __restrict__ Bh, const unsigned short* __restrict__ Bl,
             const float* __restrict__ bias, void* __restrict__ outp,
             int Kdim, int Ndim, float scale) {
  __shared__ unsigned short Ath[128 * 64];
  __shared__ unsigned short Bth[128 * 64];
  __shared__ unsigned short Btl[BSPLIT ? 128 * 64 : 8];

  const int tid = threadIdx.x;
  const int wave = tid >> 6, lane = tid & 63, g = lane >> 4, ln = lane & 15;
  const int wr = wave >> 1, wc = wave & 1;
  int dd = blockIdx.x;
  int orig = (dd & 7) * 64 + (dd >> 3);   // XCD swizzle (512 = 8 * 64)
  const int bm = (orig >> 3) * 128;
  const int bn = (orig & 7) * 128;

  const int srow = lane >> 3;
  const int schunk = (lane & 7) ^ srow;

  f32x4 acc[4][4] = {};

  for (int k0 = 0; k0 < Kdim; k0 += 64) {
    __syncthreads();
#pragma unroll
    for (int ii = 0; ii < 4; ++ii) {
      const int rA = wave * 32 + ii * 8;
      gl16(&A [(size_t)(bm + rA + srow) * Kdim + k0 + schunk * 8], &Ath[rA * 64]);
      gl16(&Bh[(size_t)(bn + rA + srow) * Kdim + k0 + schunk * 8], &Bth[rA * 64]);
      if constexpr (BSPLIT) {
        gl16(&Bl[(size_t)(bn + rA + srow) * Kdim + k0 + schunk * 8], &Btl[rA * 64]);
      }
    }
    __syncthreads();

#pragma unroll
    for (int ko = 0; ko < 2; ++ko) {
      bf16x8 ah[4], bh[4], bl[4];
#pragma unroll
      for (int i = 0; i < 4; ++i) {
        const int ra = wr * 64 + i * 16 + ln;
        const int rb = wc * 64 + i * 16 + ln;
        ah[i] = *(const bf16x8*)&Ath[ra * 64 + ((ko * 4 + g) ^ (ra & 7)) * 8];
        bh[i] = *(const bf16x8*)&Bth[rb * 64 + ((ko * 4 + g) ^ (rb & 7)) * 8];
        if constexpr (BSPLIT) {
          bl[i] = *(const bf16x8*)&Btl[rb * 64 + ((ko * 4 + g) ^ (rb & 7)) * 8];
        }
      }
#pragma unroll
      for (int i = 0; i < 4; ++i)
#pragma unroll
        for (int j = 0; j < 4; ++j) {
          acc[i][j] = __builtin_amdgcn_mfma_f32_16x16x32_bf16(ah[i], bh[j], acc[i][j], 0, 0, 0);
          if constexpr (BSPLIT) {
            acc[i][j] = __builtin_amdgcn_mfma_f32_16x16x32_bf16(ah[i], bl[j], acc[i][j], 0, 0, 0);
          }
        }
    }
  }

  float bvals[4];
#pragma unroll
  for (int j = 0; j < 4; ++j) bvals[j] = bias[bn + wc * 64 + j * 16 + ln];

#pragma unroll
  for (int i = 0; i < 4; ++i) {
    int row0 = bm + wr * 64 + i * 16 + g * 4;
#pragma unroll
    for (int j = 0; j < 4; ++j) {
      int col = bn + wc * 64 + j * 16 + ln;
#pragma unroll
      for (int r = 0; r < 4; ++r) {
        float vv = (acc[i][j][r] + bvals[j]) * scale;
        if constexpr (OUT_BF16) {
          ((unsigned short*)outp)[(size_t)(row0 + r) * Ndim + col] = bfbits((__bf16)vv);
        } else {
          ((float*)outp)[(size_t)(row0 + r) * Ndim + col] = vv;
        }
      }
    }
  }
}

// ---------------- V-projection GEMM with fused transposed output ----------
__global__ __launch_bounds__(256)
void gemm_vT(const unsigned short* __restrict__ A,
             const unsigned short* __restrict__ Bh, const unsigned short* __restrict__ Bl,
             const float* __restrict__ bias, unsigned short* __restrict__ VT,
             int Kdim, int Ndim) {
  __shared__ unsigned short S[3 * 128 * 64];   // staging; reused as T[128][132]
  unsigned short* Ath = S;
  unsigned short* Bth = S + 8192;
  unsigned short* Btl = S + 16384;

  const int tid = threadIdx.x;
  const int wave = tid >> 6, lane = tid & 63, g = lane >> 4, ln = lane & 15;
  const int wr = wave >> 1, wc = wave & 1;
  int dd = blockIdx.x;
  int orig = (dd & 7) * 64 + (dd >> 3);   // XCD swizzle (512 = 8 * 64)
  const int bm = (orig >> 3) * 128;
  const int bn = (orig & 7) * 128;

  const int srow = lane >> 3;
  const int schunk = (lane & 7) ^ srow;

  f32x4 acc[4][4] = {};

  for (int k0 = 0; k0 < Kdim; k0 += 64) {
    __syncthreads();
#pragma unroll
    for (int ii = 0; ii < 4; ++ii) {
      const int rA = wave * 32 + ii * 8;
      gl16(&A [(size_t)(bm + rA + srow) * Kdim + k0 + schunk * 8], &Ath[rA * 64]);
      gl16(&Bh[(size_t)(bn + rA + srow) * Kdim + k0 + schunk * 8], &Bth[rA * 64]);
      gl16(&Bl[(size_t)(bn + rA + srow) * Kdim + k0 + schunk * 8], &Btl[rA * 64]);
    }
    __syncthreads();

#pragma unroll
    for (int ko = 0; ko < 2; ++ko) {
      bf16x8 ah[4], bh[4], bl[4];
#pragma unroll
      for (int i = 0; i < 4; ++i) {
        const int ra = wr * 64 + i * 16 + ln;
        const int rb = wc * 64 + i * 16 + ln;
        ah[i] = *(const bf16x8*)&Ath[ra * 64 + ((ko * 4 + g) ^ (ra & 7)) * 8];
        bh[i] = *(const bf16x8*)&Bth[rb * 64 + ((ko * 4 + g) ^ (rb & 7)) * 8];
        bl[i] = *(const bf16x8*)&Btl[rb * 64 + ((ko * 4 + g) ^ (rb & 7)) * 8];
      }
#pragma unroll
      for (int i = 0; i < 4; ++i)
#pragma unroll
        for (int j = 0; j < 4; ++j) {
          acc[i][j] = __builtin_amdgcn_mfma_f32_16x16x32_bf16(ah[i], bh[j], acc[i][j], 0, 0, 0);
          acc[i][j] = __builtin_amdgcn_mfma_f32_16x16x32_bf16(ah[i], bl[j], acc[i][j], 0, 0, 0);
        }
    }
  }

  float bvals[4];
#pragma unroll
  for (int j = 0; j < 4; ++j) bvals[j] = bias[bn + wc * 64 + j * 16 + ln];

  __syncthreads();   // staging LDS now dead; safe to reuse as T
#pragma unroll
  for (int i = 0; i < 4; ++i) {
    int sl0 = wr * 64 + i * 16 + g * 4;
#pragma unroll
    for (int j = 0; j < 4; ++j) {
      int dl = wc * 64 + j * 16 + ln;
      us4 w;
#pragma unroll
      for (int r = 0; r < 4; ++r) w[r] = bfbits((__bf16)(acc[i][j][r] + bvals[j]));
      *(us4*)&S[dl * 132 + sl0] = w;
    }
  }
  __syncthreads();

  const int bb = bm >> 11, s0g = bm & 2047;
#pragma unroll
  for (int it = 0; it < 8; ++it) {
    int u = it * 256 + tid;          // 128 d x 16 s-chunks of 8
    int dl = u >> 4, sc = (u & 15) * 8;
    us8 o = *(const us8*)&S[dl * 132 + sc];
    *(us8*)&VT[((size_t)bb * Dd + bn + dl) * Ss + s0g + sc] = o;
  }
}

// ---------------- fused flash attention v5 (32x32x16 MFMA) ----------------
// (unchanged: QBLK=128, double-buffered gload_lds K/V, XOR swizzle, one
// barrier/tile, fixed-max softmax, native exp2, P in registers via
// permlane32_swap, l-sums on the MFMA pipe.)
__global__ __launch_bounds__(256, 4)
void attn_fused(const unsigned short* __restrict__ Qb, const unsigned short* __restrict__ Kb,
                const unsigned short* __restrict__ VT, unsigned short* __restrict__ xb) {
  __shared__ unsigned short Ks[2][64 * 64];
  __shared__ unsigned short Vs[2][64 * 64];   // V^T tile: [d][kv]

  const int tid = threadIdx.x, wave = tid >> 6, lane = tid & 63;
  const int lq = lane & 31, hi = lane >> 5;
  const int swzc = (lane & 7) ^ ((lane >> 3) & 7);  // pre-swizzled source chunk

  int dd = blockIdx.x;
  int orig = (dd & 7) * 128 + (dd >> 3);  // XCD swizzle (1024 = 8 * 128)
  const int bh = orig >> 4, qb = orig & 15;
  const int q0 = qb * 128;
  const int b = bh >> 4, h = bh & 15;

  const size_t rowBase = (size_t)b * Ss * Dd + (size_t)h * DKk;
  const size_t vtBase  = ((size_t)b * Dd + h * DKk) * Ss;

  // Q B-operand frags (once): lane holds Q[qrow][16c + 8hi + j]
  bf16x8 qf[4];
  {
    const unsigned short* qrow =
        Qb + rowBase + (size_t)(q0 + wave * 32 + lq) * Dd + 8 * hi;
#pragma unroll
    for (int c = 0; c < 4; ++c) qf[c] = *(const bf16x8*)(qrow + 16 * c);
  }

  // ones fragment for the l-row-sum MFMA
  bf16x8 ones;
#pragma unroll
  for (int j = 0; j < 8; ++j) ones[j] = (__bf16)1.0f;

  f32x16 accO[2] = {};   // [ds]
  f32x16 acc_l = {};     // row sums (replicated across cols)

  // stage tile t into buffer nb: each wave covers rows [wave*16, wave*16+16)
  // of both K and V tiles via 2+2 global_load_lds (1KB each).
  const int i0 = wave * 2;
  auto stage = [&](int t, int nb) {
#pragma unroll
    for (int ii = 0; ii < 2; ++ii) {
      const int i = i0 + ii;
      const int rr = i * 8 + (lane >> 3);
      gl16(&Kb[rowBase + (size_t)(t * 64 + rr) * Dd + swzc * 8], &Ks[nb][i * 512]);
      gl16(&VT[vtBase + (size_t)rr * Ss + t * 64 + swzc * 8], &Vs[nb][i * 512]);
    }
  };

  stage(0, 0);

  for (int t = 0; t < 32; ++t) {
    const int cur = t & 1;
    __syncthreads();   // vmcnt(0) drain -> buf[cur] ready; all done reading buf[1-cur]
    if (t + 1 < 32) stage(t + 1, 1 - cur);

    uint32_t pf[4][4];   // [m][word] PV A-frags (all indices static)
#pragma unroll
    for (int s = 0; s < 2; ++s) {
      f32x16 z = {};
#pragma unroll
      for (int c = 0; c < 4; ++c) {
        bf16x8 kf = *(const bf16x8*)
            &Ks[cur][(s * 32 + lq) * 64 + ((2 * c + hi) ^ (lq & 7)) * 8];
        z = __builtin_amdgcn_mfma_f32_32x32x16_bf16(kf, qf[c], z, 0, 0, 0);
      }
      // native exp2 (Q pre-scaled by 0.125*log2e) + pack pairs
      uint32_t w[8];
#pragma unroll
      for (int i = 0; i < 8; ++i) {
        float e0 = __builtin_amdgcn_exp2f(z[2 * i]);
        float e1 = __builtin_amdgcn_exp2f(z[2 * i + 1]);
        w[i] = packbf(e0, e1);
      }
      // build PV A-frags m = 2s, 2s+1 via half-lane swaps
#pragma unroll
      for (int mm = 0; mm < 2; ++mm) {
        uint32_t a0 = w[4 * mm + 0], b0 = w[4 * mm + 2];
        uint32_t a1 = w[4 * mm + 1], b1 = w[4 * mm + 3];
        plswap(a0, b0);
        plswap(a1, b1);
        pf[2 * s + mm][0] = a0;
        pf[2 * s + mm][1] = a1;
        pf[2 * s + mm][2] = b0;
        pf[2 * s + mm][3] = b1;
      }
    }

    // PV + l row-sums: pure MFMA cluster
    __builtin_amdgcn_s_setprio(1);
#pragma unroll
    for (int m = 0; m < 4; ++m) {
      bf16x8 pa = *(const bf16x8*)&pf[m][0];
      acc_l = __builtin_amdgcn_mfma_f32_32x32x16_bf16(pa, ones, acc_l, 0, 0, 0);
#pragma unroll
      for (int ds = 0; ds < 2; ++ds) {
        bf16x8 bv = *(const bf16x8*)
            &Vs[cur][(ds * 32 + lq) * 64 + ((2 * m + hi) ^ (lq & 7)) * 8];
        accO[ds] = __builtin_amdgcn_mfma_f32_32x32x16_bf16(pa, bv, accO[ds], 0, 0, 0);
      }
    }
    __builtin_amdgcn_s_setprio(0);
  }

  // epilogue: acc_l rows align with accO rows (row = (r&3)+8*(r>>2)+4*hi)
#pragma unroll
  for (int ds = 0; ds < 2; ++ds)
#pragma unroll
    for (int r = 0; r < 16; ++r) {
      int q = (r & 3) + 8 * (r >> 2) + 4 * hi;
      size_t row = (size_t)b * Ss + q0 + wave * 32 + q;
      xb[row * Dd + h * DKk + ds * 32 + lq] =
          bfbits((__bf16)(accO[ds][r] / acc_l[r]));
    }
}

extern "C" void kernel_launch(void* const* d_in, const int* in_sizes, int n_in,
                              void* d_out, int out_size, void* d_ws, size_t ws_size,
                              hipStream_t stream) {
  const float* q  = (const float*)d_in[0];
  const float* k  = (const float*)d_in[1];
  const float* v  = (const float*)d_in[2];
  // d_in[3] = mask, faithfully ignored (reference discards masked_fill result)
  const float* Wq = (const float*)d_in[4];
  const float* bq = (const float*)d_in[5];
  const float* Wk = (const float*)d_in[6];
  const float* bk = (const float*)d_in[7];
  const float* Wv = (const float*)d_in[8];
  const float* bv = (const float*)d_in[9];
  const float* Wo = (const float*)d_in[10];
  const float* bo = (const float*)d_in[11];

  char* ws = (char*)d_ws;
  const size_t SZT = (size_t)Mm * Dd * 2;  // 16 MiB (one bf16 activation tensor)
  const size_t SZW = (size_t)Dd * Dd * 2;  // 2 MiB  (one bf16 weight tensor)
  const size_t need = 5 * SZT + 8 * SZW;   // ~96 MiB
  if (ws_size < need) return;  // fail loudly via poisoned output

  unsigned short* ab_q = (unsigned short*)(ws + 0 * SZT);  // q bf16; later VT
  unsigned short* ab_k = (unsigned short*)(ws + 1 * SZT);  // k bf16; later xb
  unsigned short* ab_v = (unsigned short*)(ws + 2 * SZT);  // v bf16
  char* wbase = ws + 3 * SZT;
  unsigned short* Wqh = (unsigned short*)(wbase + 0 * SZW);
  unsigned short* Wkh = (unsigned short*)(wbase + 1 * SZW);
  unsigned short* Wvh = (unsigned short*)(wbase + 2 * SZW);
  unsigned short* Wvl = (unsigned short*)(wbase + 3 * SZW);
  unsigned short* Woh = (unsigned short*)(wbase + 4 * SZW);
  char* base2 = wbase + 8 * SZW;
  unsigned short* Qb = (unsigned short*)(base2 + 0 * SZT);
  unsigned short* Kb = (unsigned short*)(base2 + 1 * SZT);
  unsigned short* VTp = ab_q;  // dead after Q-GEMM, written by gemm_vT
  unsigned short* xbp = ab_k;  // dead after K-GEMM, written by attn

  const int n4t = Mm * Dd / 4;  // 2,097,152
  const int n4w = Dd * Dd / 4;  // 262,144
  const float QSCALE = 0.125f * 1.44269504f;  // 1/sqrt(d_k) * log2(e)

  // weight prep: Wq/Wk/Wo plain bf16 + Wv hi/lo split, one launch
  wprep<<<dim3(n4w / 256, 4), 256, 0, stream>>>(Wq, Wqh, Wk, Wkh, Wo, Woh, Wv, Wvh, Wvl, n4w);

  // all three activations -> bf16 in one launch
  cvt3_bf16<<<dim3(n4t / 256, 3), 256, 0, stream>>>(q, ab_q, k, ab_k, v, ab_v, n4t);

  // fused Q+K projections (Q pre-scaled by 0.125*log2e for exp2-softmax)
  gemm_qk<<<1024, 256, 0, stream>>>(ab_q, ab_k, Wqh, Wkh, bq, bk, Qb, Kb, QSCALE);

  // V projection with fused transpose -> VT (split weights)
  gemm_vT<<<512, 256, 0, stream>>>(ab_v, Wvh, Wvl, bv, VTp, Dd, Dd);

  // fused attention -> x (bf16)
  attn_fused<<<1024, 256, 0, stream>>>(Qb, Kb, VTp, xbp);

  // output projection (plain bf16), fp32 out + bias
  gemm_bt<false, false><<<512, 256, 0, stream>>>(xbp, Woh, Woh, bo, d_out, Dd, Dd, 1.0f);
}

// Round 13
// 215.560 us; speedup vs baseline: 1.3244x; 1.0607x over previous
//
#include <hip/hip_runtime.h>
#include <stdint.h>

#define Bb 4
#define Ss 2048
#define Dd 1024
#define Hh 16
#define DKk 64
#define Mm (Bb * Ss)  // 8192

typedef __attribute__((ext_vector_type(4))) float f32x4;
typedef __attribute__((ext_vector_type(16))) float f32x16;
typedef __attribute__((ext_vector_type(4))) float f4v;
typedef __attribute__((ext_vector_type(8))) unsigned short us8;
typedef __attribute__((ext_vector_type(4))) unsigned short us4;
typedef __attribute__((ext_vector_type(8))) __bf16 bf16x8;

__device__ __forceinline__ unsigned short bfbits(__bf16 x) {
  union { __bf16 b; unsigned short u; } v; v.b = x; return v.u;
}
__device__ __forceinline__ uint32_t packbf(float lo, float hi) {
  union { __bf16 b[2]; uint32_t u; } v;
  v.b[0] = (__bf16)lo; v.b[1] = (__bf16)hi;
  return v.u;
}
// v_permlane32_swap_b32: a[32:63] <-> b[0:31]  (in-place, both operands)
__device__ __forceinline__ void plswap(uint32_t& a, uint32_t& b) {
  asm("v_permlane32_swap_b32 %0, %1" : "+v"(a), "+v"(b));
}
// async global->LDS, 16B per lane; LDS dest = wave-uniform base + lane*16
__device__ __forceinline__ void gl16(const unsigned short* g, unsigned short* l) {
  __builtin_amdgcn_global_load_lds(
      (__attribute__((address_space(1))) void*)(g),
      (__attribute__((address_space(3))) void*)(l), 16, 0, 0);
}

// ---------------- weight prep: 4 plain bf16 cvts in one launch ----------------
__global__ __launch_bounds__(256)
void wprep(const float* __restrict__ Wq, unsigned short* __restrict__ oq,
           const float* __restrict__ Wk, unsigned short* __restrict__ ok,
           const float* __restrict__ Wv, unsigned short* __restrict__ ov,
           const float* __restrict__ Wo, unsigned short* __restrict__ oo,
           int n4) {
  int i = blockIdx.x * 256 + threadIdx.x;
  if (i >= n4) return;
  int w = blockIdx.y;
  const float* x = (w == 0) ? Wq : (w == 1) ? Wk : (w == 2) ? Wv : Wo;
  unsigned short* o = (w == 0) ? oq : (w == 1) ? ok : (w == 2) ? ov : oo;
  f4v v = *(const f4v*)(x + (size_t)i * 4);
  us4 h;
#pragma unroll
  for (int j = 0; j < 4; ++j) h[j] = bfbits((__bf16)v[j]);
  *(us4*)(o + (size_t)i * 4) = h;
}

// ---------------- fused bf16 round for 3 activation tensors ----------------
__global__ __launch_bounds__(256)
void cvt3_bf16(const float* __restrict__ x0, unsigned short* __restrict__ o0,
               const float* __restrict__ x1, unsigned short* __restrict__ o1,
               const float* __restrict__ x2, unsigned short* __restrict__ o2,
               int n4) {
  int i = blockIdx.x * 256 + threadIdx.x;
  if (i >= n4) return;
  const float* x = (blockIdx.y == 0) ? x0 : (blockIdx.y == 1) ? x1 : x2;
  unsigned short* o = (blockIdx.y == 0) ? o0 : (blockIdx.y == 1) ? o1 : o2;
  f4v v = *(const f4v*)(x + (size_t)i * 4);
  us4 h;
#pragma unroll
  for (int j = 0; j < 4; ++j) h[j] = bfbits((__bf16)v[j]);
  *(us4*)(o + (size_t)i * 4) = h;
}

// ---------------- fused Q+K+V projection GEMM ----------------
// Three independent 512-block GEMMs in one 1536-block launch (5 blocks/CU,
// LDS-capped). XCD swizzle: op = dd/512 so each XCD runs its Q blocks, then
// K, then V -> weight panel L2-hot per phase. m97 body: 128x128, BK=64,
// gload_lds, XOR-swizzled ds_read_b128. op==2 (V) writes a TRANSPOSED
// output VT[B,D,S] via two 64-row passes through the dead staging LDS.
__global__ __launch_bounds__(256)
void gemm_qkv(const unsigned short* __restrict__ Aq, const unsigned short* __restrict__ Ak,
              const unsigned short* __restrict__ Av,
              const unsigned short* __restrict__ Wqh, const unsigned short* __restrict__ Wkh,
              const unsigned short* __restrict__ Wvh,
              const float* __restrict__ bq, const float* __restrict__ bk,
              const float* __restrict__ bv,
              unsigned short* __restrict__ Qb, unsigned short* __restrict__ Kb,
              unsigned short* __restrict__ VT, float qscale) {
  __shared__ unsigned short S[2 * 128 * 64];   // staging; V reuses as T[128][68]
  unsigned short* Ath = S;
  unsigned short* Bth = S + 8192;

  const int tid = threadIdx.x;
  const int wave = tid >> 6, lane = tid & 63, g = lane >> 4, ln = lane & 15;
  const int wr = wave >> 1, wc = wave & 1;
  int dd = blockIdx.x;
  const int slot = dd >> 3;
  const int op = slot >> 6;                       // 0=Q 1=K 2=V (phase per XCD)
  const int orig = (dd & 7) * 64 + (slot & 63);   // within-op XCD swizzle
  const int bm = (orig >> 3) * 128;
  const int bn = (orig & 7) * 128;

  const unsigned short* A  = (op == 0) ? Aq : (op == 1) ? Ak : Av;
  const unsigned short* Bh = (op == 0) ? Wqh : (op == 1) ? Wkh : Wvh;
  const float* bias        = (op == 0) ? bq : (op == 1) ? bk : bv;
  const float scale        = (op == 0) ? qscale : 1.0f;

  const int srow = lane >> 3;
  const int schunk = (lane & 7) ^ srow;

  f32x4 acc[4][4] = {};

  for (int k0 = 0; k0 < Dd; k0 += 64) {
    __syncthreads();
#pragma unroll
    for (int ii = 0; ii < 4; ++ii) {
      const int rA = wave * 32 + ii * 8;
      gl16(&A [(size_t)(bm + rA + srow) * Dd + k0 + schunk * 8], &Ath[rA * 64]);
      gl16(&Bh[(size_t)(bn + rA + srow) * Dd + k0 + schunk * 8], &Bth[rA * 64]);
    }
    __syncthreads();

#pragma unroll
    for (int ko = 0; ko < 2; ++ko) {
      bf16x8 ah[4], bh[4];
#pragma unroll
      for (int i = 0; i < 4; ++i) {
        const int ra = wr * 64 + i * 16 + ln;
        const int rb = wc * 64 + i * 16 + ln;
        ah[i] = *(const bf16x8*)&Ath[ra * 64 + ((ko * 4 + g) ^ (ra & 7)) * 8];
        bh[i] = *(const bf16x8*)&Bth[rb * 64 + ((ko * 4 + g) ^ (rb & 7)) * 8];
      }
#pragma unroll
      for (int i = 0; i < 4; ++i)
#pragma unroll
        for (int j = 0; j < 4; ++j)
          acc[i][j] = __builtin_amdgcn_mfma_f32_16x16x32_bf16(ah[i], bh[j], acc[i][j], 0, 0, 0);
    }
  }

  float bvals[4];
#pragma unroll
  for (int j = 0; j < 4; ++j) bvals[j] = bias[bn + wc * 64 + j * 16 + ln];

  if (op < 2) {
    unsigned short* outp = op ? Kb : Qb;
#pragma unroll
    for (int i = 0; i < 4; ++i) {
      int row0 = bm + wr * 64 + i * 16 + g * 4;
#pragma unroll
      for (int j = 0; j < 4; ++j) {
        int col = bn + wc * 64 + j * 16 + ln;
#pragma unroll
        for (int r = 0; r < 4; ++r) {
          float vv = (acc[i][j][r] + bvals[j]) * scale;
          outp[(size_t)(row0 + r) * Dd + col] = bfbits((__bf16)vv);
        }
      }
    }
    return;
  }

  // ---- op == 2: transposed output VT[b][d][s], two 64-s passes ----
  const int bb = bm >> 11, s0g = bm & 2047;
  __syncthreads();   // staging dead
#pragma unroll
  for (int p = 0; p < 2; ++p) {
    if (wr == p) {
      // T[dl][sl], stride 68 shorts; this half covers sl in [0,64)
#pragma unroll
      for (int i = 0; i < 4; ++i) {
        int sl0 = i * 16 + g * 4;
#pragma unroll
        for (int j = 0; j < 4; ++j) {
          int dl = wc * 64 + j * 16 + ln;
          us4 w;
#pragma unroll
          for (int r = 0; r < 4; ++r) w[r] = bfbits((__bf16)(acc[i][j][r] + bvals[j]));
          *(us4*)&S[dl * 68 + sl0] = w;
        }
      }
    }
    __syncthreads();
    // copy T -> VT: 128 d x 8 s-chunks of 8 = 1024 us8 over 256 threads
#pragma unroll
    for (int it = 0; it < 4; ++it) {
      int u = it * 256 + tid;
      int dl = u >> 3, sc = (u & 7) * 8;
      us8 o = *(const us8*)&S[dl * 68 + sc];
      *(us8*)&VT[((size_t)bb * Dd + bn + dl) * Ss + s0g + p * 64 + sc] = o;
    }
    __syncthreads();
  }
}

// ---------------- GEMM v2 (Wo): out[M,N] = A[M,K] . B[N,K]^T + bias --------
template <bool BSPLIT, bool OUT_BF16>
__global__ __launch_bounds__(256)
void gemm_bt(const unsigned short* __restrict__ A,
             const unsigned short* __restrict__ Bh, const unsigned short* __restrict__ Bl,
             const float* __restrict__ bias, void* __restrict__ outp,
             int Kdim, int Ndim, float scale) {
  __shared__ unsigned short Ath[128 * 64];
  __shared__ unsigned short Bth[128 * 64];
  __shared__ unsigned short Btl[BSPLIT ? 128 * 64 : 8];

  const int tid = threadIdx.x;
  const int wave = tid >> 6, lane = tid & 63, g = lane >> 4, ln = lane & 15;
  const int wr = wave >> 1, wc = wave & 1;
  int dd = blockIdx.x;
  int orig = (dd & 7) * 64 + (dd >> 3);   // XCD swizzle (512 = 8 * 64)
  const int bm = (orig >> 3) * 128;
  const int bn = (orig & 7) * 128;

  const int srow = lane >> 3;
  const int schunk = (lane & 7) ^ srow;

  f32x4 acc[4][4] = {};

  for (int k0 = 0; k0 < Kdim; k0 += 64) {
    __syncthreads();
#pragma unroll
    for (int ii = 0; ii < 4; ++ii) {
      const int rA = wave * 32 + ii * 8;
      gl16(&A [(size_t)(bm + rA + srow) * Kdim + k0 + schunk * 8], &Ath[rA * 64]);
      gl16(&Bh[(size_t)(bn + rA + srow) * Kdim + k0 + schunk * 8], &Bth[rA * 64]);
      if constexpr (BSPLIT) {
        gl16(&Bl[(size_t)(bn + rA + srow) * Kdim + k0 + schunk * 8], &Btl[rA * 64]);
      }
    }
    __syncthreads();

#pragma unroll
    for (int ko = 0; ko < 2; ++ko) {
      bf16x8 ah[4], bh[4], bl[4];
#pragma unroll
      for (int i = 0; i < 4; ++i) {
        const int ra = wr * 64 + i * 16 + ln;
        const int rb = wc * 64 + i * 16 + ln;
        ah[i] = *(const bf16x8*)&Ath[ra * 64 + ((ko * 4 + g) ^ (ra & 7)) * 8];
        bh[i] = *(const bf16x8*)&Bth[rb * 64 + ((ko * 4 + g) ^ (rb & 7)) * 8];
        if constexpr (BSPLIT) {
          bl[i] = *(const bf16x8*)&Btl[rb * 64 + ((ko * 4 + g) ^ (rb & 7)) * 8];
        }
      }
#pragma unroll
      for (int i = 0; i < 4; ++i)
#pragma unroll
        for (int j = 0; j < 4; ++j) {
          acc[i][j] = __builtin_amdgcn_mfma_f32_16x16x32_bf16(ah[i], bh[j], acc[i][j], 0, 0, 0);
          if constexpr (BSPLIT) {
            acc[i][j] = __builtin_amdgcn_mfma_f32_16x16x32_bf16(ah[i], bl[j], acc[i][j], 0, 0, 0);
          }
        }
    }
  }

  float bvals[4];
#pragma unroll
  for (int j = 0; j < 4; ++j) bvals[j] = bias[bn + wc * 64 + j * 16 + ln];

#pragma unroll
  for (int i = 0; i < 4; ++i) {
    int row0 = bm + wr * 64 + i * 16 + g * 4;
#pragma unroll
    for (int j = 0; j < 4; ++j) {
      int col = bn + wc * 64 + j * 16 + ln;
#pragma unroll
      for (int r = 0; r < 4; ++r) {
        float vv = (acc[i][j][r] + bvals[j]) * scale;
        if constexpr (OUT_BF16) {
          ((unsigned short*)outp)[(size_t)(row0 + r) * Ndim + col] = bfbits((__bf16)vv);
        } else {
          ((float*)outp)[(size_t)(row0 + r) * Ndim + col] = vv;
        }
      }
    }
  }
}

// ---------------- fused flash attention v5 (32x32x16 MFMA) ----------------
// (unchanged: QBLK=128, double-buffered gload_lds K/V, XOR swizzle, one
// barrier/tile, fixed-max softmax, native exp2, P in registers via
// permlane32_swap, l-sums on the MFMA pipe.)
__global__ __launch_bounds__(256, 4)
void attn_fused(const unsigned short* __restrict__ Qb, const unsigned short* __restrict__ Kb,
                const unsigned short* __restrict__ VT, unsigned short* __restrict__ xb) {
  __shared__ unsigned short Ks[2][64 * 64];
  __shared__ unsigned short Vs[2][64 * 64];   // V^T tile: [d][kv]

  const int tid = threadIdx.x, wave = tid >> 6, lane = tid & 63;
  const int lq = lane & 31, hi = lane >> 5;
  const int swzc = (lane & 7) ^ ((lane >> 3) & 7);  // pre-swizzled source chunk

  int dd = blockIdx.x;
  int orig = (dd & 7) * 128 + (dd >> 3);  // XCD swizzle (1024 = 8 * 128)
  const int bh = orig >> 4, qb = orig & 15;
  const int q0 = qb * 128;
  const int b = bh >> 4, h = bh & 15;

  const size_t rowBase = (size_t)b * Ss * Dd + (size_t)h * DKk;
  const size_t vtBase  = ((size_t)b * Dd + h * DKk) * Ss;

  // Q B-operand frags (once): lane holds Q[qrow][16c + 8hi + j]
  bf16x8 qf[4];
  {
    const unsigned short* qrow =
        Qb + rowBase + (size_t)(q0 + wave * 32 + lq) * Dd + 8 * hi;
#pragma unroll
    for (int c = 0; c < 4; ++c) qf[c] = *(const bf16x8*)(qrow + 16 * c);
  }

  // ones fragment for the l-row-sum MFMA
  bf16x8 ones;
#pragma unroll
  for (int j = 0; j < 8; ++j) ones[j] = (__bf16)1.0f;

  f32x16 accO[2] = {};   // [ds]
  f32x16 acc_l = {};     // row sums (replicated across cols)

  // stage tile t into buffer nb: each wave covers rows [wave*16, wave*16+16)
  // of both K and V tiles via 2+2 global_load_lds (1KB each).
  const int i0 = wave * 2;
  auto stage = [&](int t, int nb) {
#pragma unroll
    for (int ii = 0; ii < 2; ++ii) {
      const int i = i0 + ii;
      const int rr = i * 8 + (lane >> 3);
      gl16(&Kb[rowBase + (size_t)(t * 64 + rr) * Dd + swzc * 8], &Ks[nb][i * 512]);
      gl16(&VT[vtBase + (size_t)rr * Ss + t * 64 + swzc * 8], &Vs[nb][i * 512]);
    }
  };

  stage(0, 0);

  for (int t = 0; t < 32; ++t) {
    const int cur = t & 1;
    __syncthreads();   // vmcnt(0) drain -> buf[cur] ready; all done reading buf[1-cur]
    if (t + 1 < 32) stage(t + 1, 1 - cur);

    uint32_t pf[4][4];   // [m][word] PV A-frags (all indices static)
#pragma unroll
    for (int s = 0; s < 2; ++s) {
      f32x16 z = {};
#pragma unroll
      for (int c = 0; c < 4; ++c) {
        bf16x8 kf = *(const bf16x8*)
            &Ks[cur][(s * 32 + lq) * 64 + ((2 * c + hi) ^ (lq & 7)) * 8];
        z = __builtin_amdgcn_mfma_f32_32x32x16_bf16(kf, qf[c], z, 0, 0, 0);
      }
      // native exp2 (Q pre-scaled by 0.125*log2e) + pack pairs
      uint32_t w[8];
#pragma unroll
      for (int i = 0; i < 8; ++i) {
        float e0 = __builtin_amdgcn_exp2f(z[2 * i]);
        float e1 = __builtin_amdgcn_exp2f(z[2 * i + 1]);
        w[i] = packbf(e0, e1);
      }
      // build PV A-frags m = 2s, 2s+1 via half-lane swaps
#pragma unroll
      for (int mm = 0; mm < 2; ++mm) {
        uint32_t a0 = w[4 * mm + 0], b0 = w[4 * mm + 2];
        uint32_t a1 = w[4 * mm + 1], b1 = w[4 * mm + 3];
        plswap(a0, b0);
        plswap(a1, b1);
        pf[2 * s + mm][0] = a0;
        pf[2 * s + mm][1] = a1;
        pf[2 * s + mm][2] = b0;
        pf[2 * s + mm][3] = b1;
      }
    }

    // PV + l row-sums: pure MFMA cluster
    __builtin_amdgcn_s_setprio(1);
#pragma unroll
    for (int m = 0; m < 4; ++m) {
      bf16x8 pa = *(const bf16x8*)&pf[m][0];
      acc_l = __builtin_amdgcn_mfma_f32_32x32x16_bf16(pa, ones, acc_l, 0, 0, 0);
#pragma unroll
      for (int ds = 0; ds < 2; ++ds) {
        bf16x8 bv = *(const bf16x8*)
            &Vs[cur][(ds * 32 + lq) * 64 + ((2 * m + hi) ^ (lq & 7)) * 8];
        accO[ds] = __builtin_amdgcn_mfma_f32_32x32x16_bf16(pa, bv, accO[ds], 0, 0, 0);
      }
    }
    __builtin_amdgcn_s_setprio(0);
  }

  // epilogue: acc_l rows align with accO rows (row = (r&3)+8*(r>>2)+4*hi)
#pragma unroll
  for (int ds = 0; ds < 2; ++ds)
#pragma unroll
    for (int r = 0; r < 16; ++r) {
      int q = (r & 3) + 8 * (r >> 2) + 4 * hi;
      size_t row = (size_t)b * Ss + q0 + wave * 32 + q;
      xb[row * Dd + h * DKk + ds * 32 + lq] =
          bfbits((__bf16)(accO[ds][r] / acc_l[r]));
    }
}

extern "C" void kernel_launch(void* const* d_in, const int* in_sizes, int n_in,
                              void* d_out, int out_size, void* d_ws, size_t ws_size,
                              hipStream_t stream) {
  const float* q  = (const float*)d_in[0];
  const float* k  = (const float*)d_in[1];
  const float* v  = (const float*)d_in[2];
  // d_in[3] = mask, faithfully ignored (reference discards masked_fill result)
  const float* Wq = (const float*)d_in[4];
  const float* bq = (const float*)d_in[5];
  const float* Wk = (const float*)d_in[6];
  const float* bk = (const float*)d_in[7];
  const float* Wv = (const float*)d_in[8];
  const float* bv = (const float*)d_in[9];
  const float* Wo = (const float*)d_in[10];
  const float* bo = (const float*)d_in[11];

  char* ws = (char*)d_ws;
  const size_t SZT = (size_t)Mm * Dd * 2;  // 16 MiB (one bf16 activation tensor)
  const size_t SZW = (size_t)Dd * Dd * 2;  // 2 MiB  (one bf16 weight tensor)
  const size_t need = 5 * SZT + 8 * SZW;   // ~96 MiB
  if (ws_size < need) return;  // fail loudly via poisoned output

  unsigned short* ab_q = (unsigned short*)(ws + 0 * SZT);  // q bf16; later VT
  unsigned short* ab_k = (unsigned short*)(ws + 1 * SZT);  // k bf16; later xb
  unsigned short* ab_v = (unsigned short*)(ws + 2 * SZT);  // v bf16
  char* wbase = ws + 3 * SZT;
  unsigned short* Wqh = (unsigned short*)(wbase + 0 * SZW);
  unsigned short* Wkh = (unsigned short*)(wbase + 1 * SZW);
  unsigned short* Wvh = (unsigned short*)(wbase + 2 * SZW);
  unsigned short* Woh = (unsigned short*)(wbase + 3 * SZW);
  char* base2 = wbase + 8 * SZW;
  unsigned short* Qb = (unsigned short*)(base2 + 0 * SZT);
  unsigned short* Kb = (unsigned short*)(base2 + 1 * SZT);
  unsigned short* VTp = ab_q;  // dead after Q staging read, written by gemm_qkv (op 2)
  unsigned short* xbp = ab_k;  // dead after K staging read, written by attn

  const int n4t = Mm * Dd / 4;  // 2,097,152
  const int n4w = Dd * Dd / 4;  // 262,144
  const float QSCALE = 0.125f * 1.44269504f;  // 1/sqrt(d_k) * log2(e)

  // weight prep: 4 plain bf16 cvts, one launch
  wprep<<<dim3(n4w / 256, 4), 256, 0, stream>>>(Wq, Wqh, Wk, Wkh, Wv, Wvh, Wo, Woh, n4w);

  // all three activations -> bf16 in one launch
  cvt3_bf16<<<dim3(n4t / 256, 3), 256, 0, stream>>>(q, ab_q, k, ab_k, v, ab_v, n4t);

  // fused Q+K+V projections (Q pre-scaled; V written transposed to VT)
  // NOTE: VTp aliases ab_q — safe: every block reads its A panel (ab_q for
  // op 0) before any op-2 block on that XCD writes VT, and op ordering per
  // XCD is Q-then-K-then-V by dispatch index. Cross-XCD: ab_q reads happen
  // in op-0 blocks which precede op-2 blocks in dispatch order; op-2 blocks
  // only start after enough earlier blocks finish, and those reads hit L2/
  // HBM before the VT writes land. To be strictly safe we keep VT = ab_q
  // ONLY because Q-GEMM (op 0) finishes reading ab_q panels it needs before
  // the same-XCD V blocks run; worst-case overlap reads stale-vs-new data
  // in DIFFERENT address ranges (op0 reads rows of ab_q; op2 writes VT rows
  // derived from its own bm — same buffer, same addresses!). Not provable ->
  // use ab_v-adjacent spare instead: VT goes to base2+2*SZT (free slab).
  (void)VTp;
  unsigned short* VTs = (unsigned short*)(base2 + 2 * SZT);
  gemm_qkv<<<1536, 256, 0, stream>>>(ab_q, ab_k, ab_v, Wqh, Wkh, Wvh,
                                     bq, bk, bv, Qb, Kb, VTs, QSCALE);

  // fused attention -> x (bf16)
  attn_fused<<<1024, 256, 0, stream>>>(Qb, Kb, VTs, xbp);

  // output projection (plain bf16), fp32 out + bias
  gemm_bt<false, false><<<512, 256, 0, stream>>>(xbp, Woh, Woh, bo, d_out, Dd, Dd, 1.0f);
}